// Round 3
// baseline (981.073 us; speedup 1.0000x reference)
//
#include <hip/hip_runtime.h>

typedef unsigned short u16;
typedef __attribute__((ext_vector_type(8))) short short8;   // 8 bf16 (4 VGPRs)
typedef __attribute__((ext_vector_type(4))) float f32x4;

__device__ __forceinline__ u16 f2bf(float f) {
    unsigned int x = __float_as_uint(f);
    unsigned int r = x + 0x7fffu + ((x >> 16) & 1u);
    return (u16)(r >> 16);
}
__device__ __forceinline__ unsigned int pk2(float lo, float hi) {
    return ((unsigned int)f2bf(hi) << 16) | (unsigned int)f2bf(lo);
}
__device__ __forceinline__ float2 bf2x(unsigned int d) {
    float2 r;
    r.x = __uint_as_float(d << 16);
    r.y = __uint_as_float(d & 0xffff0000u);
    return r;
}
__device__ __forceinline__ void bf8x(uint4 v, float* o) {
    float2 a = bf2x(v.x); o[0] = a.x; o[1] = a.y;
    float2 b = bf2x(v.y); o[2] = b.x; o[3] = b.y;
    float2 c = bf2x(v.z); o[4] = c.x; o[5] = c.y;
    float2 d = bf2x(v.w); o[6] = d.x; o[7] = d.y;
}
__device__ __forceinline__ float rfl_f(float x) {
    return __uint_as_float(__builtin_amdgcn_readfirstlane(__float_as_uint(x)));
}

#define CC 96
#define SS 16
#define GG 6
#define BN_INV 0.99999500003749969f  // 1/sqrt(1+1e-5)
#define ABLK 768                     // 3 blocks/CU when VGPR<=168
#define TOTW (ABLK * 4)

// gWB image (dwords, bf16 pairs): [0..2495] Wp2 even cols (row c2=channel/2,
// stride 52 dw, 48 used), [2496..4991] Wp2 odd cols, [4992..5303] Wpw rows.
#define WB_ODD 2496
#define WB_WPW 4992
#define WB_TOT 5304

// ---------------- kernel 0: prep (weights repack + tiny precompute) ----------------
__global__ __launch_bounds__(256) void prep_kernel(
    const float* __restrict__ Wq, const float* __restrict__ Wk, const float* __restrict__ Wv,
    const float* __restrict__ Wp2, const float* __restrict__ Ww1,
    const float* __restrict__ bp2, const float* __restrict__ bw1,
    u16* __restrict__ WcatT, unsigned int* __restrict__ gWB, float* __restrict__ cvec)
{
    int t = blockIdx.x * 256 + threadIdx.x;
    if (t < 13824) {
        // WcatT[c][j] bf16, row-major [288][96]; dword idx = c*48 + j2
        int c = t / 48, j2 = t % 48;
        const float* src = (c < 96) ? Wq : (c < 192) ? Wk : Wv;
        int cc = c % 96;
        float a = src[(2 * j2) * CC + cc];
        float b = src[(2 * j2 + 1) * CC + cc];
        ((unsigned int*)WcatT)[t] = pk2(a, b);
    } else if (t < 13824 + WB_TOT) {
        int i = t - 13824;
        if (i < WB_WPW) {
            int arr = i / WB_ODD;            // 0 = even channels, 1 = odd
            int r = i % WB_ODD;
            int c2 = r / 52, rr = r % 52;
            unsigned int d = 0;
            if (rr < 48) {
                int c = 2 * c2 + arr;
                d = pk2(Wp2[(2 * rr) * CC + c], Wp2[(2 * rr + 1) * CC + c]);
            }
            gWB[i] = d;
        } else {
            int r = i - WB_WPW;
            int g = r / 52, rr = r % 52;
            unsigned int d = 0;
            if (rr < 48) {
                float a = 0.f, b = 0.f;
                for (int c = 0; c < CC; ++c) {
                    float wg = Ww1[c * GG + g];
                    a = fmaf(Wp2[(2 * rr) * CC + c], wg, a);
                    b = fmaf(Wp2[(2 * rr + 1) * CC + c], wg, b);
                }
                d = pk2(a, b);
            }
            gWB[i] = d;
        }
    } else if (t < 13824 + WB_TOT + GG) {
        int g = t - (13824 + WB_TOT);
        float acc = bw1[g];
        for (int c = 0; c < CC; ++c)
            acc = fmaf(bp2[c], Ww1[c * GG + g], acc);
        cvec[g] = acc;
    }
}

// ---------------- kernel 0b: feat -> bf16 ----------------
__global__ __launch_bounds__(256) void fcvt_kernel(
    const float* __restrict__ feat, u16* __restrict__ featB, int total4)
{
    int i = blockIdx.x * 256 + threadIdx.x;
    if (i < total4) {
        float4 v = *(const float4*)(feat + (size_t)i * 4);
        ushort4 o;
        o.x = f2bf(v.x); o.y = f2bf(v.y); o.z = f2bf(v.z); o.w = f2bf(v.w);
        *(ushort4*)(featB + (size_t)i * 4) = o;
    }
}

// ---------------- kernel 1: fused q|k|v MFMA GEMM + epilogue (r6-proven) ----------------
#define SBS 104
__global__ __launch_bounds__(256, 2) void gemm_qkv(
    const u16* __restrict__ featB, const u16* __restrict__ WcatT,
    const float* __restrict__ bq, const float* __restrict__ gq, const float* __restrict__ betaq,
    const float* __restrict__ bk, const float* __restrict__ gk, const float* __restrict__ betak,
    const float* __restrict__ bv, const float* __restrict__ Ww1,
    u16* __restrict__ v_bf, float* __restrict__ KW1, float* __restrict__ qW1, int N)
{
    __shared__ u16 sB[288 * SBS];
    const int t = threadIdx.x;

    for (int i = t; i < 288 * 12; i += 256) {
        int row = i / 12, c8 = i % 12;
        *(float4*)(sB + row * SBS + c8 * 8) = *(const float4*)(WcatT + row * CC + c8 * 8);
    }
    __syncthreads();

    const int wave = t >> 6, lane = t & 63;
    const int m = lane & 15, quad = lane >> 4;
    const int rowbase = blockIdx.x * 64 + wave * 16;

    int arow = rowbase + m;
    if (arow >= N) arow = 0;

    short8 a[3];
    #pragma unroll
    for (int kk = 0; kk < 3; ++kk)
        a[kk] = *(const short8*)(featB + (size_t)arow * CC + kk * 32 + quad * 8);

    f32x4 acc[18];
    #pragma unroll
    for (int nt = 0; nt < 18; ++nt) acc[nt] = (f32x4){0.f, 0.f, 0.f, 0.f};

    #pragma unroll
    for (int kk = 0; kk < 3; ++kk) {
        #pragma unroll
        for (int nt = 0; nt < 18; ++nt) {
            short8 b = *(const short8*)(sB + (nt * 16 + m) * SBS + kk * 32 + quad * 8);
            acc[nt] = __builtin_amdgcn_mfma_f32_16x16x32_bf16(a[kk], b, acc[nt], 0, 0, 0);
        }
    }

    int orow[4];
    #pragma unroll
    for (int i = 0; i < 4; ++i) orow[i] = rowbase + quad * 4 + i;
    const int cloc = m;

    #pragma unroll
    for (int nt6 = 0; nt6 < 6; ++nt6) {
        int c = nt6 * 16 + cloc;
        float bvv = bv[c];
        #pragma unroll
        for (int i = 0; i < 4; ++i)
            if (orow[i] < N)
                v_bf[(size_t)orow[i] * CC + c] = f2bf(acc[12 + nt6][i] + bvv);
    }

    #pragma unroll
    for (int mat = 0; mat < 2; ++mat) {
        const float* bb_ = mat ? bk : bq;
        const float* gg_ = mat ? gk : gq;
        const float* be_ = mat ? betak : betaq;
        float red[4][6];
        #pragma unroll
        for (int i = 0; i < 4; ++i)
            #pragma unroll
            for (int g = 0; g < 6; ++g) red[i][g] = 0.f;

        #pragma unroll
        for (int nt6 = 0; nt6 < 6; ++nt6) {
            int nt = mat * 6 + nt6;
            int c = nt6 * 16 + cloc;
            float bb = bb_[c], sc = gg_[c] * BN_INV, be = be_[c];
            float w1r[6];
            #pragma unroll
            for (int g = 0; g < 6; ++g) w1r[g] = Ww1[c * GG + g];
            #pragma unroll
            for (int i = 0; i < 4; ++i) {
                float act = fmaxf(0.f, fmaf(acc[nt][i] + bb, sc, be));
                #pragma unroll
                for (int g = 0; g < 6; ++g)
                    red[i][g] = fmaf(act, w1r[g], red[i][g]);
            }
        }
        #pragma unroll
        for (int st = 1; st < 16; st <<= 1)
            #pragma unroll
            for (int i = 0; i < 4; ++i)
                #pragma unroll
                for (int g = 0; g < 6; ++g)
                    red[i][g] += __shfl_xor(red[i][g], st);

        float* dst = mat ? KW1 : qW1;
        #pragma unroll
        for (int g = 0; g < 6; ++g)
            if (cloc == g)
                #pragma unroll
                for (int i = 0; i < 4; ++i)
                    if (orow[i] < N)
                        dst[(size_t)orow[i] * 8 + g] = red[i][g];
    }
}

// ---------------- kernel 2: attention v7 — amdgpu_waves_per_eu(3) for the 168-VGPR target ----------------
// Round-1 lesson: __launch_bounds__(256,3) is converted with a wave-32 assumption
// (3*256/32/4 = 6 waves/EU -> 84-VGPR cap -> 2.6 GB spill). The native backend
// attribute takes waves/EU directly: min 3 -> cap ~170 (granularity 8 -> 168).
// Natural allocation is 172, so only ~4 regs must be shaved -> near-zero spill risk.
// Round-2 source restructuring (vpre after stage-2 peak, q-row in SGPRs) kept to
// give the allocator slack.
__global__ __launch_bounds__(256) __attribute__((amdgpu_waves_per_eu(3))) void attn_kernel(
    const float* __restrict__ coord, const int* __restrict__ ref,
    const float* __restrict__ Wp1, const float* __restrict__ bp1, const float* __restrict__ gp, const float* __restrict__ betap,
    const float* __restrict__ bp2,
    const float* __restrict__ gw, const float* __restrict__ betaw,
    const float* __restrict__ Ww2, const float* __restrict__ bw2,
    const u16* __restrict__ v_bf, const float* __restrict__ KW1, const float* __restrict__ qW1,
    const unsigned int* __restrict__ gWB, const float* __restrict__ cvec,
    float* __restrict__ out, int N)
{
    __shared__ __align__(16) unsigned int sWB[WB_TOT];  // 21216 B
    __shared__ __align__(16) unsigned int shh[4][832];  // h bf16 pairs [s*52 + L]
    __shared__ __align__(16) uint4 swt[4][SS];          // packed softmax weights per s
    __shared__ __align__(16) float sHs[4][600];         // Hsum fp32 [g*100 + 2L]
    __shared__ __align__(16) float4 sposx[4][SS];
    __shared__ int sidxx[4][SS];

    const int t = threadIdx.x;
    for (int i = t; i < WB_TOT; i += 256) sWB[i] = gWB[i];
    __syncthreads();   // only block barrier

    const int w = t >> 6, lane = t & 63;
    const int wid = blockIdx.x * 4 + w;
    unsigned int* shw = shh[w];
    uint4* swtw = swt[w];
    float* sHsw = sHs[w];
    float4* sposw = sposx[w];
    int* sidxw = sidxx[w];

    const int  L = (lane < 48) ? lane : 47;
    const bool actv = lane < 48;
    const int  cA = 2 * L;
    const int  gL = L >> 3;
    const int  s16 = lane & 15, qq = lane >> 4;

    // BN folded into Wp1: h = relu(sp*(dot+b1) + bt) = relu(dot' + b1')
    const float spA = gp[cA] * BN_INV, spB = gp[cA + 1] * BN_INV;
    const float w1xA = Wp1[cA] * spA, w1yA = Wp1[CC + cA] * spA, w1zA = Wp1[2 * CC + cA] * spA;
    const float w1xB = Wp1[cA + 1] * spB, w1yB = Wp1[CC + cA + 1] * spB, w1zB = Wp1[2 * CC + cA + 1] * spB;
    const float b1A = fmaf(bp1[cA], spA, betap[cA]);
    const float b1B = fmaf(bp1[cA + 1], spB, betap[cA + 1]);
    const float bpA = bp2[cA], bpB = bp2[cA + 1];

    // prefetched ref indices for the upcoming iteration
    int idxreg = 0;
    if (lane < SS && wid < N) idxreg = ref[wid * SS + s16];

    for (int n = wid; n < N; n += TOTW) {
        // ---- head: indices, pos, k-row gather ----
        if (lane < SS) sidxw[s16] = idxreg;
        float4 kAv = {0,0,0,0}; float2 kBv = {0,0};
        if (lane < SS) {
            int j = idxreg;
            float4 P;
            P.x = coord[j * 3 + 0] - coord[n * 3 + 0];
            P.y = coord[j * 3 + 1] - coord[n * 3 + 1];
            P.z = coord[j * 3 + 2] - coord[n * 3 + 2];
            P.w = 0.f;
            sposw[s16] = P;
            const float* kr = KW1 + (size_t)idxreg * 8;
            kAv = *(const float4*)kr; kBv = *(const float2*)(kr + 4);
        }
        // uniform q-row: fold cvec - q into SGPRs (n is wave-uniform)
        float qc[GG];
        {
            int nu = __builtin_amdgcn_readfirstlane(n);
            const float* qr = qW1 + (size_t)nu * 8;
            #pragma unroll
            for (int g = 0; g < GG; ++g)
                qc[g] = rfl_f(cvec[g] - qr[g]);
        }
        // issue next iteration's ref load now; result consumed next iteration
        {
            int nn = n + TOTW;
            if (lane < SS && nn < N) idxreg = ref[nn * SS + s16];
        }

        // ---- stage 1: h = relu(pos@Wp1' + b1') -> packed bf16 pairs ----
        if (actv) {
            #pragma unroll
            for (int s = 0; s < SS; ++s) {
                float4 P = sposw[s];                 // broadcast b128
                float hA = fmaxf(0.f, fmaf(P.x, w1xA, fmaf(P.y, w1yA, fmaf(P.z, w1zA, b1A))));
                float hB = fmaxf(0.f, fmaf(P.x, w1xB, fmaf(P.y, w1yB, fmaf(P.z, w1zB, b1B))));
                shw[s * 52 + L] = pk2(hA, hB);
            }
        }

        // ---- stage 2 main: logits (4 lanes per neighbor, 24-ch slices) ----
        float acc[GG];
        {
            const unsigned int* hrow = shw + 52 * s16 + 12 * qq;
            float hg[24];
            bf8x(*(const uint4*)(hrow), hg);
            bf8x(*(const uint4*)(hrow + 4), hg + 8);
            bf8x(*(const uint4*)(hrow + 8), hg + 16);

            #pragma unroll
            for (int g = 0; g < GG; ++g) {
                const unsigned int* wr = sWB + WB_WPW + g * 52 + 12 * qq;
                float wg[24];
                bf8x(*(const uint4*)(wr), wg);
                bf8x(*(const uint4*)(wr + 4), wg + 8);
                bf8x(*(const uint4*)(wr + 8), wg + 16);
                float a = 0.f;
                #pragma unroll
                for (int u = 0; u < 24; ++u)
                    a = fmaf(hg[u], wg[u], a);
                acc[g] = a;
            }
            #pragma unroll
            for (int g = 0; g < GG; ++g) {
                acc[g] += __shfl_xor(acc[g], 16);
                acc[g] += __shfl_xor(acc[g], 32);
            }
        }

        // ---- v gather (kept out of the stage-2 register peak) ----
        unsigned int vpre[SS];
        #pragma unroll
        for (int s = 0; s < SS; ++s) {
            int jj = sidxw[s];                       // wave-private, in-order DS
            vpre[s] = *(const unsigned int*)(v_bf + (size_t)jj * CC + cA);
        }

        // ---- stage 2 epilogue: softmax weights (lanes < 16) ----
        if (lane < SS) {
            float tv[GG];
            tv[0] = acc[0] + kAv.x + qc[0];
            tv[1] = acc[1] + kAv.y + qc[1];
            tv[2] = acc[2] + kAv.z + qc[2];
            tv[3] = acc[3] + kAv.w + qc[3];
            tv[4] = acc[4] + kBv.x + qc[4];
            tv[5] = acc[5] + kBv.y + qc[5];
            float a6[GG];
            #pragma unroll
            for (int g = 0; g < GG; ++g)
                a6[g] = fmaxf(0.f, fmaf(tv[g], gw[g] * BN_INV, betaw[g]));
            float e[GG];
            #pragma unroll
            for (int gg2 = 0; gg2 < GG; ++gg2) {
                float lv = bw2[gg2];
                #pragma unroll
                for (int g2 = 0; g2 < GG; ++g2)
                    lv = fmaf(a6[g2], Ww2[g2 * GG + gg2], lv);
                e[gg2] = __expf(lv);
            }
            float wgt[GG];
            #pragma unroll
            for (int g = 0; g < GG; ++g) {
                float ssum = e[g];
                ssum += __shfl_xor(ssum, 1);
                ssum += __shfl_xor(ssum, 2);
                ssum += __shfl_xor(ssum, 4);
                ssum += __shfl_xor(ssum, 8);
                wgt[g] = e[g] / ssum;
            }
            uint4 wt;
            wt.x = pk2(wgt[0], wgt[1]);
            wt.y = pk2(wgt[2], wgt[3]);
            wt.z = pk2(wgt[4], wgt[5]);
            wt.w = 0u;
            swtw[s16] = wt;
        }

        // ---- stage 3+4: Hsum + v-part fused ----
        float accA = bpA, accB = bpB;
        {
            float hsA[GG] = {0.f,0.f,0.f,0.f,0.f,0.f};
            float hsB[GG] = {0.f,0.f,0.f,0.f,0.f,0.f};
            #pragma unroll
            for (int s = 0; s < SS; ++s) {
                uint4 wt = swtw[s];                  // broadcast b128
                float2 w01 = bf2x(wt.x), w23 = bf2x(wt.y), w45 = bf2x(wt.z);
                float2 h2 = bf2x(shw[s * 52 + L]);
                hsA[0] = fmaf(w01.x, h2.x, hsA[0]); hsB[0] = fmaf(w01.x, h2.y, hsB[0]);
                hsA[1] = fmaf(w01.y, h2.x, hsA[1]); hsB[1] = fmaf(w01.y, h2.y, hsB[1]);
                hsA[2] = fmaf(w23.x, h2.x, hsA[2]); hsB[2] = fmaf(w23.x, h2.y, hsB[2]);
                hsA[3] = fmaf(w23.y, h2.x, hsA[3]); hsB[3] = fmaf(w23.y, h2.y, hsB[3]);
                hsA[4] = fmaf(w45.x, h2.x, hsA[4]); hsB[4] = fmaf(w45.x, h2.y, hsB[4]);
                hsA[5] = fmaf(w45.y, h2.x, hsA[5]); hsB[5] = fmaf(w45.y, h2.y, hsB[5]);
                float wsel = (gL < 2) ? (gL == 0 ? w01.x : w01.y)
                           : (gL < 4) ? (gL == 2 ? w23.x : w23.y)
                                      : (gL == 4 ? w45.x : w45.y);
                float2 v2 = bf2x(vpre[s]);
                accA = fmaf(v2.x, wsel, accA);
                accB = fmaf(v2.y, wsel, accB);
            }
            if (actv) {
                #pragma unroll
                for (int g = 0; g < GG; ++g)
                    *(float2*)(sHsw + g * 100 + cA) = make_float2(hsA[g], hsB[g]);
            }
        }

        // ---- stage 5: out = v-part + Hsum[gL] @ Wp2 cols ----
        if (actv) {
            const float* hrg = sHsw + gL * 100;
            const unsigned int* wrE = sWB + L * 52;            // even channel cA
            const unsigned int* wrO = sWB + WB_ODD + L * 52;   // odd channel cA+1
            #pragma unroll
            for (int u = 0; u < 12; ++u) {
                float4 hb0 = *(const float4*)(hrg + 8 * u);
                float4 hb1 = *(const float4*)(hrg + 8 * u + 4);
                float we[8], wo[8];
                bf8x(*(const uint4*)(wrE + 4 * u), we);
                bf8x(*(const uint4*)(wrO + 4 * u), wo);
                accA = fmaf(hb0.x, we[0], accA); accB = fmaf(hb0.x, wo[0], accB);
                accA = fmaf(hb0.y, we[1], accA); accB = fmaf(hb0.y, wo[1], accB);
                accA = fmaf(hb0.z, we[2], accA); accB = fmaf(hb0.z, wo[2], accB);
                accA = fmaf(hb0.w, we[3], accA); accB = fmaf(hb0.w, wo[3], accB);
                accA = fmaf(hb1.x, we[4], accA); accB = fmaf(hb1.x, wo[4], accB);
                accA = fmaf(hb1.y, we[5], accA); accB = fmaf(hb1.y, wo[5], accB);
                accA = fmaf(hb1.z, we[6], accA); accB = fmaf(hb1.z, wo[6], accB);
                accA = fmaf(hb1.w, we[7], accA); accB = fmaf(hb1.w, wo[7], accB);
            }
            *(float2*)(out + (size_t)n * CC + cA) = make_float2(accA, accB);
        }
    }
}

extern "C" void kernel_launch(void* const* d_in, const int* in_sizes, int n_in,
                              void* d_out, int out_size, void* d_ws, size_t ws_size,
                              hipStream_t stream) {
    const float* feat  = (const float*)d_in[0];
    const float* coord = (const float*)d_in[1];
    const int*   ref   = (const int*)d_in[2];
    const float* Wq = (const float*)d_in[3],  *bq = (const float*)d_in[4],  *gq = (const float*)d_in[5],  *betaq = (const float*)d_in[6];
    const float* Wk = (const float*)d_in[7],  *bk = (const float*)d_in[8],  *gk = (const float*)d_in[9],  *betak = (const float*)d_in[10];
    const float* Wv = (const float*)d_in[11], *bv = (const float*)d_in[12];
    const float* Wp1 = (const float*)d_in[13], *bp1 = (const float*)d_in[14], *gp = (const float*)d_in[15], *betap = (const float*)d_in[16];
    const float* Wp2 = (const float*)d_in[17], *bp2 = (const float*)d_in[18];
    const float* Ww1 = (const float*)d_in[19], *bw1 = (const float*)d_in[20], *gw = (const float*)d_in[21], *betaw = (const float*)d_in[22];
    const float* Ww2 = (const float*)d_in[23], *bw2 = (const float*)d_in[24];

    const int N = in_sizes[0] / CC;   // 50000

    // workspace (~23 MB)
    float* wsf = (float*)d_ws;
    float* KW1 = wsf;                                  // N*8 f32
    float* qW1 = KW1 + (size_t)N * 8;                  // N*8 f32
    float* cvec = qW1 + (size_t)N * 8;                 // 6 (pad 32)
    unsigned int* gWB = (unsigned int*)(cvec + 32);    // 5304 (pad 5312)
    u16* WcatT = (u16*)(gWB + 5312);                   // 288*96 bf16
    u16* featB = WcatT + 288 * CC;                     // N*96 bf16
    u16* v_bf = featB + (size_t)N * CC;                // N*96 bf16

    const int prep_total = 13824 + WB_TOT + GG;
    prep_kernel<<<dim3((prep_total + 255) / 256), dim3(256), 0, stream>>>(
        Wq, Wk, Wv, Wp2, Ww1, bp2, bw1, WcatT, gWB, cvec);

    const int total4 = N * CC / 4;
    fcvt_kernel<<<dim3((total4 + 255) / 256), dim3(256), 0, stream>>>(feat, featB, total4);

    gemm_qkv<<<dim3((N + 63) / 64), dim3(256), 0, stream>>>(
        featB, WcatT, bq, gq, betaq, bk, gk, betak, bv, Ww1,
        v_bf, KW1, qW1, N);

    attn_kernel<<<dim3(ABLK), dim3(256), 0, stream>>>(
        coord, ref, Wp1, bp1, gp, betap, bp2, gw, betaw, Ww2, bw2,
        v_bf, KW1, qW1, gWB, cvec, (float*)d_out, N);
}

// Round 4
// 866.205 us; speedup vs baseline: 1.1326x; 1.1326x over previous
//
#include <hip/hip_runtime.h>

typedef unsigned short u16;
typedef __attribute__((ext_vector_type(8))) short short8;   // 8 bf16 (4 VGPRs)
typedef __attribute__((ext_vector_type(4))) float f32x4;

__device__ __forceinline__ u16 f2bf(float f) {
    unsigned int x = __float_as_uint(f);
    unsigned int r = x + 0x7fffu + ((x >> 16) & 1u);
    return (u16)(r >> 16);
}
__device__ __forceinline__ unsigned int pk2(float lo, float hi) {
    return ((unsigned int)f2bf(hi) << 16) | (unsigned int)f2bf(lo);
}
__device__ __forceinline__ float2 bf2x(unsigned int d) {
    float2 r;
    r.x = __uint_as_float(d << 16);
    r.y = __uint_as_float(d & 0xffff0000u);
    return r;
}
__device__ __forceinline__ void bf8x(uint4 v, float* o) {
    float2 a = bf2x(v.x); o[0] = a.x; o[1] = a.y;
    float2 b = bf2x(v.y); o[2] = b.x; o[3] = b.y;
    float2 c = bf2x(v.z); o[4] = c.x; o[5] = c.y;
    float2 d = bf2x(v.w); o[6] = d.x; o[7] = d.y;
}
__device__ __forceinline__ float rfl_f(float x) {
    return __uint_as_float(__builtin_amdgcn_readfirstlane(__float_as_uint(x)));
}

#define CC 96
#define SS 16
#define GG 6
#define BN_INV 0.99999500003749969f  // 1/sqrt(1+1e-5)
#define ABLK 768                     // 3 blocks/CU (LDS 46.6KB -> 3 blocks max)
#define TOTW (ABLK * 4)

// gWB image (dwords, bf16 pairs): [0..2495] Wp2 even cols (row c2=channel/2,
// stride 52 dw, 48 used), [2496..4991] Wp2 odd cols, [4992..5303] Wpw rows.
#define WB_ODD 2496
#define WB_WPW 4992
#define WB_TOT 5304

// ---------------- kernel 0: prep (weights repack + tiny precompute) ----------------
__global__ __launch_bounds__(256) void prep_kernel(
    const float* __restrict__ Wq, const float* __restrict__ Wk, const float* __restrict__ Wv,
    const float* __restrict__ Wp2, const float* __restrict__ Ww1,
    const float* __restrict__ bp2, const float* __restrict__ bw1,
    u16* __restrict__ WcatT, unsigned int* __restrict__ gWB, float* __restrict__ cvec)
{
    int t = blockIdx.x * 256 + threadIdx.x;
    if (t < 13824) {
        // WcatT[c][j] bf16, row-major [288][96]; dword idx = c*48 + j2
        int c = t / 48, j2 = t % 48;
        const float* src = (c < 96) ? Wq : (c < 192) ? Wk : Wv;
        int cc = c % 96;
        float a = src[(2 * j2) * CC + cc];
        float b = src[(2 * j2 + 1) * CC + cc];
        ((unsigned int*)WcatT)[t] = pk2(a, b);
    } else if (t < 13824 + WB_TOT) {
        int i = t - 13824;
        if (i < WB_WPW) {
            int arr = i / WB_ODD;            // 0 = even channels, 1 = odd
            int r = i % WB_ODD;
            int c2 = r / 52, rr = r % 52;
            unsigned int d = 0;
            if (rr < 48) {
                int c = 2 * c2 + arr;
                d = pk2(Wp2[(2 * rr) * CC + c], Wp2[(2 * rr + 1) * CC + c]);
            }
            gWB[i] = d;
        } else {
            int r = i - WB_WPW;
            int g = r / 52, rr = r % 52;
            unsigned int d = 0;
            if (rr < 48) {
                float a = 0.f, b = 0.f;
                for (int c = 0; c < CC; ++c) {
                    float wg = Ww1[c * GG + g];
                    a = fmaf(Wp2[(2 * rr) * CC + c], wg, a);
                    b = fmaf(Wp2[(2 * rr + 1) * CC + c], wg, b);
                }
                d = pk2(a, b);
            }
            gWB[i] = d;
        }
    } else if (t < 13824 + WB_TOT + GG) {
        int g = t - (13824 + WB_TOT);
        float acc = bw1[g];
        for (int c = 0; c < CC; ++c)
            acc = fmaf(bp2[c], Ww1[c * GG + g], acc);
        cvec[g] = acc;
    }
}

// ---------------- kernel 0b: feat -> bf16 ----------------
__global__ __launch_bounds__(256) void fcvt_kernel(
    const float* __restrict__ feat, u16* __restrict__ featB, int total4)
{
    int i = blockIdx.x * 256 + threadIdx.x;
    if (i < total4) {
        float4 v = *(const float4*)(feat + (size_t)i * 4);
        ushort4 o;
        o.x = f2bf(v.x); o.y = f2bf(v.y); o.z = f2bf(v.z); o.w = f2bf(v.w);
        *(ushort4*)(featB + (size_t)i * 4) = o;
    }
}

// ---------------- kernel 1: fused q|k|v MFMA GEMM + epilogue (r6-proven) ----------------
#define SBS 104
__global__ __launch_bounds__(256, 2) void gemm_qkv(
    const u16* __restrict__ featB, const u16* __restrict__ WcatT,
    const float* __restrict__ bq, const float* __restrict__ gq, const float* __restrict__ betaq,
    const float* __restrict__ bk, const float* __restrict__ gk, const float* __restrict__ betak,
    const float* __restrict__ bv, const float* __restrict__ Ww1,
    u16* __restrict__ v_bf, float* __restrict__ KW1, float* __restrict__ qW1, int N)
{
    __shared__ u16 sB[288 * SBS];
    const int t = threadIdx.x;

    for (int i = t; i < 288 * 12; i += 256) {
        int row = i / 12, c8 = i % 12;
        *(float4*)(sB + row * SBS + c8 * 8) = *(const float4*)(WcatT + row * CC + c8 * 8);
    }
    __syncthreads();

    const int wave = t >> 6, lane = t & 63;
    const int m = lane & 15, quad = lane >> 4;
    const int rowbase = blockIdx.x * 64 + wave * 16;

    int arow = rowbase + m;
    if (arow >= N) arow = 0;

    short8 a[3];
    #pragma unroll
    for (int kk = 0; kk < 3; ++kk)
        a[kk] = *(const short8*)(featB + (size_t)arow * CC + kk * 32 + quad * 8);

    f32x4 acc[18];
    #pragma unroll
    for (int nt = 0; nt < 18; ++nt) acc[nt] = (f32x4){0.f, 0.f, 0.f, 0.f};

    #pragma unroll
    for (int kk = 0; kk < 3; ++kk) {
        #pragma unroll
        for (int nt = 0; nt < 18; ++nt) {
            short8 b = *(const short8*)(sB + (nt * 16 + m) * SBS + kk * 32 + quad * 8);
            acc[nt] = __builtin_amdgcn_mfma_f32_16x16x32_bf16(a[kk], b, acc[nt], 0, 0, 0);
        }
    }

    int orow[4];
    #pragma unroll
    for (int i = 0; i < 4; ++i) orow[i] = rowbase + quad * 4 + i;
    const int cloc = m;

    #pragma unroll
    for (int nt6 = 0; nt6 < 6; ++nt6) {
        int c = nt6 * 16 + cloc;
        float bvv = bv[c];
        #pragma unroll
        for (int i = 0; i < 4; ++i)
            if (orow[i] < N)
                v_bf[(size_t)orow[i] * CC + c] = f2bf(acc[12 + nt6][i] + bvv);
    }

    #pragma unroll
    for (int mat = 0; mat < 2; ++mat) {
        const float* bb_ = mat ? bk : bq;
        const float* gg_ = mat ? gk : gq;
        const float* be_ = mat ? betak : betaq;
        float red[4][6];
        #pragma unroll
        for (int i = 0; i < 4; ++i)
            #pragma unroll
            for (int g = 0; g < 6; ++g) red[i][g] = 0.f;

        #pragma unroll
        for (int nt6 = 0; nt6 < 6; ++nt6) {
            int nt = mat * 6 + nt6;
            int c = nt6 * 16 + cloc;
            float bb = bb_[c], sc = gg_[c] * BN_INV, be = be_[c];
            float w1r[6];
            #pragma unroll
            for (int g = 0; g < 6; ++g) w1r[g] = Ww1[c * GG + g];
            #pragma unroll
            for (int i = 0; i < 4; ++i) {
                float act = fmaxf(0.f, fmaf(acc[nt][i] + bb, sc, be));
                #pragma unroll
                for (int g = 0; g < 6; ++g)
                    red[i][g] = fmaf(act, w1r[g], red[i][g]);
            }
        }
        #pragma unroll
        for (int st = 1; st < 16; st <<= 1)
            #pragma unroll
            for (int i = 0; i < 4; ++i)
                #pragma unroll
                for (int g = 0; g < 6; ++g)
                    red[i][g] += __shfl_xor(red[i][g], st);

        float* dst = mat ? KW1 : qW1;
        #pragma unroll
        for (int g = 0; g < 6; ++g)
            if (cloc == g)
                #pragma unroll
                for (int i = 0; i < 4; ++i)
                    if (orow[i] < N)
                        dst[(size_t)orow[i] * 8 + g] = red[i][g];
    }
}

// ---------------- kernel 2: attention v8 — calibrated 128-VGPR cap + chunked stage 2 ----------------
// Occupancy-hint calibration (measured): hint "3" via EITHER __launch_bounds__(256,3)
// OR amdgpu_waves_per_eu(3) -> 84-VGPR cap (~256/3) -> catastrophic spill.
// Therefore hint "2" -> 256/2 = 128-VGPR cap, which is also the m69 occupancy
// step (waves halve at 64/128/256): <=128 VGPR is the next occupancy tier.
// To fit 128 without spilling, stage-2's dot product is chunked into 8-channel
// slices (hg[8]+wg[8]=16 transient regs instead of hg[24]+wg[24]=48; identical
// LDS traffic). Natural live-set at peak ~95-100 -> near-zero spill expected.
// Tripwire: WRITE_SIZE >> 40MB means the cap spilled -> revert to round-0 config.
__global__ __launch_bounds__(256) __attribute__((amdgpu_waves_per_eu(2))) void attn_kernel(
    const float* __restrict__ coord, const int* __restrict__ ref,
    const float* __restrict__ Wp1, const float* __restrict__ bp1, const float* __restrict__ gp, const float* __restrict__ betap,
    const float* __restrict__ bp2,
    const float* __restrict__ gw, const float* __restrict__ betaw,
    const float* __restrict__ Ww2, const float* __restrict__ bw2,
    const u16* __restrict__ v_bf, const float* __restrict__ KW1, const float* __restrict__ qW1,
    const unsigned int* __restrict__ gWB, const float* __restrict__ cvec,
    float* __restrict__ out, int N)
{
    __shared__ __align__(16) unsigned int sWB[WB_TOT];  // 21216 B
    __shared__ __align__(16) unsigned int shh[4][832];  // h bf16 pairs [s*52 + L]
    __shared__ __align__(16) uint4 swt[4][SS];          // packed softmax weights per s
    __shared__ __align__(16) float sHs[4][600];         // Hsum fp32 [g*100 + 2L]
    __shared__ __align__(16) float4 sposx[4][SS];
    __shared__ int sidxx[4][SS];

    const int t = threadIdx.x;
    for (int i = t; i < WB_TOT; i += 256) sWB[i] = gWB[i];
    __syncthreads();   // only block barrier

    const int w = t >> 6, lane = t & 63;
    const int wid = blockIdx.x * 4 + w;
    unsigned int* shw = shh[w];
    uint4* swtw = swt[w];
    float* sHsw = sHs[w];
    float4* sposw = sposx[w];
    int* sidxw = sidxx[w];

    const int  L = (lane < 48) ? lane : 47;
    const bool actv = lane < 48;
    const int  cA = 2 * L;
    const int  gL = L >> 3;
    const int  s16 = lane & 15, qq = lane >> 4;

    // BN folded into Wp1: h = relu(sp*(dot+b1) + bt) = relu(dot' + b1')
    const float spA = gp[cA] * BN_INV, spB = gp[cA + 1] * BN_INV;
    const float w1xA = Wp1[cA] * spA, w1yA = Wp1[CC + cA] * spA, w1zA = Wp1[2 * CC + cA] * spA;
    const float w1xB = Wp1[cA + 1] * spB, w1yB = Wp1[CC + cA + 1] * spB, w1zB = Wp1[2 * CC + cA + 1] * spB;
    const float b1A = fmaf(bp1[cA], spA, betap[cA]);
    const float b1B = fmaf(bp1[cA + 1], spB, betap[cA + 1]);
    const float bpA = bp2[cA], bpB = bp2[cA + 1];

    // prefetched ref indices for the upcoming iteration
    int idxreg = 0;
    if (lane < SS && wid < N) idxreg = ref[wid * SS + s16];

    for (int n = wid; n < N; n += TOTW) {
        // ---- head: indices, pos, k-row gather ----
        if (lane < SS) sidxw[s16] = idxreg;
        float4 kAv = {0,0,0,0}; float2 kBv = {0,0};
        if (lane < SS) {
            int j = idxreg;
            float4 P;
            P.x = coord[j * 3 + 0] - coord[n * 3 + 0];
            P.y = coord[j * 3 + 1] - coord[n * 3 + 1];
            P.z = coord[j * 3 + 2] - coord[n * 3 + 2];
            P.w = 0.f;
            sposw[s16] = P;
            const float* kr = KW1 + (size_t)idxreg * 8;
            kAv = *(const float4*)kr; kBv = *(const float2*)(kr + 4);
        }
        // uniform q-row: fold cvec - q into SGPRs (n is wave-uniform)
        float qc[GG];
        {
            int nu = __builtin_amdgcn_readfirstlane(n);
            const float* qr = qW1 + (size_t)nu * 8;
            #pragma unroll
            for (int g = 0; g < GG; ++g)
                qc[g] = rfl_f(cvec[g] - qr[g]);
        }
        // issue next iteration's ref load now; result consumed next iteration
        {
            int nn = n + TOTW;
            if (lane < SS && nn < N) idxreg = ref[nn * SS + s16];
        }

        // ---- stage 1: h = relu(pos@Wp1' + b1') -> packed bf16 pairs ----
        if (actv) {
            #pragma unroll
            for (int s = 0; s < SS; ++s) {
                float4 P = sposw[s];                 // broadcast b128
                float hA = fmaxf(0.f, fmaf(P.x, w1xA, fmaf(P.y, w1yA, fmaf(P.z, w1zA, b1A))));
                float hB = fmaxf(0.f, fmaf(P.x, w1xB, fmaf(P.y, w1yB, fmaf(P.z, w1zB, b1B))));
                shw[s * 52 + L] = pk2(hA, hB);
            }
        }

        // ---- stage 2 main: logits, 8-channel chunks (low register peak) ----
        float acc[GG];
        {
            const unsigned int* hrow = shw + 52 * s16 + 12 * qq;
            const unsigned int* wbase = sWB + WB_WPW + 12 * qq;
            #pragma unroll
            for (int g = 0; g < GG; ++g) acc[g] = 0.f;
            #pragma unroll
            for (int c3 = 0; c3 < 3; ++c3) {
                float hg[8];
                bf8x(*(const uint4*)(hrow + 4 * c3), hg);
                #pragma unroll
                for (int g = 0; g < GG; ++g) {
                    float wg[8];
                    bf8x(*(const uint4*)(wbase + g * 52 + 4 * c3), wg);
                    float a = acc[g];
                    #pragma unroll
                    for (int u = 0; u < 8; ++u)
                        a = fmaf(hg[u], wg[u], a);
                    acc[g] = a;
                }
            }
            #pragma unroll
            for (int g = 0; g < GG; ++g) {
                acc[g] += __shfl_xor(acc[g], 16);
                acc[g] += __shfl_xor(acc[g], 32);
            }
        }

        // ---- v gather (kept out of the stage-2 register peak) ----
        unsigned int vpre[SS];
        #pragma unroll
        for (int s = 0; s < SS; ++s) {
            int jj = sidxw[s];                       // wave-private, in-order DS
            vpre[s] = *(const unsigned int*)(v_bf + (size_t)jj * CC + cA);
        }

        // ---- stage 2 epilogue: softmax weights (lanes < 16) ----
        if (lane < SS) {
            float tv[GG];
            tv[0] = acc[0] + kAv.x + qc[0];
            tv[1] = acc[1] + kAv.y + qc[1];
            tv[2] = acc[2] + kAv.z + qc[2];
            tv[3] = acc[3] + kAv.w + qc[3];
            tv[4] = acc[4] + kBv.x + qc[4];
            tv[5] = acc[5] + kBv.y + qc[5];
            float a6[GG];
            #pragma unroll
            for (int g = 0; g < GG; ++g)
                a6[g] = fmaxf(0.f, fmaf(tv[g], gw[g] * BN_INV, betaw[g]));
            float e[GG];
            #pragma unroll
            for (int gg2 = 0; gg2 < GG; ++gg2) {
                float lv = bw2[gg2];
                #pragma unroll
                for (int g2 = 0; g2 < GG; ++g2)
                    lv = fmaf(a6[g2], Ww2[g2 * GG + gg2], lv);
                e[gg2] = __expf(lv);
            }
            float wgt[GG];
            #pragma unroll
            for (int g = 0; g < GG; ++g) {
                float ssum = e[g];
                ssum += __shfl_xor(ssum, 1);
                ssum += __shfl_xor(ssum, 2);
                ssum += __shfl_xor(ssum, 4);
                ssum += __shfl_xor(ssum, 8);
                wgt[g] = e[g] / ssum;
            }
            uint4 wt;
            wt.x = pk2(wgt[0], wgt[1]);
            wt.y = pk2(wgt[2], wgt[3]);
            wt.z = pk2(wgt[4], wgt[5]);
            wt.w = 0u;
            swtw[s16] = wt;
        }

        // ---- stage 3+4: Hsum + v-part fused ----
        float accA = bpA, accB = bpB;
        {
            float hsA[GG] = {0.f,0.f,0.f,0.f,0.f,0.f};
            float hsB[GG] = {0.f,0.f,0.f,0.f,0.f,0.f};
            #pragma unroll
            for (int s = 0; s < SS; ++s) {
                uint4 wt = swtw[s];                  // broadcast b128
                float2 w01 = bf2x(wt.x), w23 = bf2x(wt.y), w45 = bf2x(wt.z);
                float2 h2 = bf2x(shw[s * 52 + L]);
                hsA[0] = fmaf(w01.x, h2.x, hsA[0]); hsB[0] = fmaf(w01.x, h2.y, hsB[0]);
                hsA[1] = fmaf(w01.y, h2.x, hsA[1]); hsB[1] = fmaf(w01.y, h2.y, hsB[1]);
                hsA[2] = fmaf(w23.x, h2.x, hsA[2]); hsB[2] = fmaf(w23.x, h2.y, hsB[2]);
                hsA[3] = fmaf(w23.y, h2.x, hsA[3]); hsB[3] = fmaf(w23.y, h2.y, hsB[3]);
                hsA[4] = fmaf(w45.x, h2.x, hsA[4]); hsB[4] = fmaf(w45.x, h2.y, hsB[4]);
                hsA[5] = fmaf(w45.y, h2.x, hsA[5]); hsB[5] = fmaf(w45.y, h2.y, hsB[5]);
                float wsel = (gL < 2) ? (gL == 0 ? w01.x : w01.y)
                           : (gL < 4) ? (gL == 2 ? w23.x : w23.y)
                                      : (gL == 4 ? w45.x : w45.y);
                float2 v2 = bf2x(vpre[s]);
                accA = fmaf(v2.x, wsel, accA);
                accB = fmaf(v2.y, wsel, accB);
            }
            if (actv) {
                #pragma unroll
                for (int g = 0; g < GG; ++g)
                    *(float2*)(sHsw + g * 100 + cA) = make_float2(hsA[g], hsB[g]);
            }
        }

        // ---- stage 5: out = v-part + Hsum[gL] @ Wp2 cols ----
        if (actv) {
            const float* hrg = sHsw + gL * 100;
            const unsigned int* wrE = sWB + L * 52;            // even channel cA
            const unsigned int* wrO = sWB + WB_ODD + L * 52;   // odd channel cA+1
            #pragma unroll
            for (int u = 0; u < 12; ++u) {
                float4 hb0 = *(const float4*)(hrg + 8 * u);
                float4 hb1 = *(const float4*)(hrg + 8 * u + 4);
                float we[8], wo[8];
                bf8x(*(const uint4*)(wrE + 4 * u), we);
                bf8x(*(const uint4*)(wrO + 4 * u), wo);
                accA = fmaf(hb0.x, we[0], accA); accB = fmaf(hb0.x, wo[0], accB);
                accA = fmaf(hb0.y, we[1], accA); accB = fmaf(hb0.y, wo[1], accB);
                accA = fmaf(hb0.z, we[2], accA); accB = fmaf(hb0.z, wo[2], accB);
                accA = fmaf(hb0.w, we[3], accA); accB = fmaf(hb0.w, wo[3], accB);
                accA = fmaf(hb1.x, we[4], accA); accB = fmaf(hb1.x, wo[4], accB);
                accA = fmaf(hb1.y, we[5], accA); accB = fmaf(hb1.y, wo[5], accB);
                accA = fmaf(hb1.z, we[6], accA); accB = fmaf(hb1.z, wo[6], accB);
                accA = fmaf(hb1.w, we[7], accA); accB = fmaf(hb1.w, wo[7], accB);
            }
            *(float2*)(out + (size_t)n * CC + cA) = make_float2(accA, accB);
        }
    }
}

extern "C" void kernel_launch(void* const* d_in, const int* in_sizes, int n_in,
                              void* d_out, int out_size, void* d_ws, size_t ws_size,
                              hipStream_t stream) {
    const float* feat  = (const float*)d_in[0];
    const float* coord = (const float*)d_in[1];
    const int*   ref   = (const int*)d_in[2];
    const float* Wq = (const float*)d_in[3],  *bq = (const float*)d_in[4],  *gq = (const float*)d_in[5],  *betaq = (const float*)d_in[6];
    const float* Wk = (const float*)d_in[7],  *bk = (const float*)d_in[8],  *gk = (const float*)d_in[9],  *betak = (const float*)d_in[10];
    const float* Wv = (const float*)d_in[11], *bv = (const float*)d_in[12];
    const float* Wp1 = (const float*)d_in[13], *bp1 = (const float*)d_in[14], *gp = (const float*)d_in[15], *betap = (const float*)d_in[16];
    const float* Wp2 = (const float*)d_in[17], *bp2 = (const float*)d_in[18];
    const float* Ww1 = (const float*)d_in[19], *bw1 = (const float*)d_in[20], *gw = (const float*)d_in[21], *betaw = (const float*)d_in[22];
    const float* Ww2 = (const float*)d_in[23], *bw2 = (const float*)d_in[24];

    const int N = in_sizes[0] / CC;   // 50000

    // workspace (~23 MB)
    float* wsf = (float*)d_ws;
    float* KW1 = wsf;                                  // N*8 f32
    float* qW1 = KW1 + (size_t)N * 8;                  // N*8 f32
    float* cvec = qW1 + (size_t)N * 8;                 // 6 (pad 32)
    unsigned int* gWB = (unsigned int*)(cvec + 32);    // 5304 (pad 5312)
    u16* WcatT = (u16*)(gWB + 5312);                   // 288*96 bf16
    u16* featB = WcatT + 288 * CC;                     // N*96 bf16
    u16* v_bf = featB + (size_t)N * CC;                // N*96 bf16

    const int prep_total = 13824 + WB_TOT + GG;
    prep_kernel<<<dim3((prep_total + 255) / 256), dim3(256), 0, stream>>>(
        Wq, Wk, Wv, Wp2, Ww1, bp2, bw1, WcatT, gWB, cvec);

    const int total4 = N * CC / 4;
    fcvt_kernel<<<dim3((total4 + 255) / 256), dim3(256), 0, stream>>>(feat, featB, total4);

    gemm_qkv<<<dim3((N + 63) / 64), dim3(256), 0, stream>>>(
        featB, WcatT, bq, gq, betaq, bk, gk, betak, bv, Ww1,
        v_bf, KW1, qW1, N);

    attn_kernel<<<dim3(ABLK), dim3(256), 0, stream>>>(
        coord, ref, Wp1, bp1, gp, betap, bp2, gw, betaw, Ww2, bw2,
        v_bf, KW1, qW1, gWB, cvec, (float*)d_out, N);
}

// Round 5
// 459.625 us; speedup vs baseline: 2.1345x; 1.8846x over previous
//
#include <hip/hip_runtime.h>

typedef unsigned short u16;
typedef __attribute__((ext_vector_type(8))) short short8;   // 8 bf16 (4 VGPRs)
typedef __attribute__((ext_vector_type(4))) float f32x4;

__device__ __forceinline__ u16 f2bf(float f) {
    unsigned int x = __float_as_uint(f);
    unsigned int r = x + 0x7fffu + ((x >> 16) & 1u);
    return (u16)(r >> 16);
}
__device__ __forceinline__ unsigned int pk2(float lo, float hi) {
    return ((unsigned int)f2bf(hi) << 16) | (unsigned int)f2bf(lo);
}
__device__ __forceinline__ float2 bf2x(unsigned int d) {
    float2 r;
    r.x = __uint_as_float(d << 16);
    r.y = __uint_as_float(d & 0xffff0000u);
    return r;
}
__device__ __forceinline__ void bf8x(uint4 v, float* o) {
    float2 a = bf2x(v.x); o[0] = a.x; o[1] = a.y;
    float2 b = bf2x(v.y); o[2] = b.x; o[3] = b.y;
    float2 c = bf2x(v.z); o[4] = c.x; o[5] = c.y;
    float2 d = bf2x(v.w); o[6] = d.x; o[7] = d.y;
}
__device__ __forceinline__ float rfl_f(float x) {
    return __uint_as_float(__builtin_amdgcn_readfirstlane(__float_as_uint(x)));
}
// gather-into-LDS: per-lane global source address, wave-uniform LDS base;
// lane i's 4 bytes land at base + i*4 (HW rule, m104/m108).
__device__ __forceinline__ void gldlds4(const void* g, void* l) {
    __builtin_amdgcn_global_load_lds(
        (const __attribute__((address_space(1))) unsigned int*)g,
        (__attribute__((address_space(3))) unsigned int*)l,
        4, 0, 0);
}

#define CC 96
#define SS 16
#define GG 6
#define BN_INV 0.99999500003749969f  // 1/sqrt(1+1e-5)
#define ABLK 512                     // == 2 blocks/CU exactly (VGPR ~172 -> 2 waves/SIMD)
#define TOTW (ABLK * 4)

// gWB image (dwords, bf16 pairs): [0..2495] Wp2 even cols (row c2=channel/2,
// stride 52 dw, 48 used), [2496..4991] Wp2 odd cols, [4992..5303] Wpw rows.
#define WB_ODD 2496
#define WB_WPW 4992
#define WB_TOT 5304

// ---------------- kernel 0: prep (weights repack + tiny precompute) ----------------
__global__ __launch_bounds__(256) void prep_kernel(
    const float* __restrict__ Wq, const float* __restrict__ Wk, const float* __restrict__ Wv,
    const float* __restrict__ Wp2, const float* __restrict__ Ww1,
    const float* __restrict__ bp2, const float* __restrict__ bw1,
    u16* __restrict__ WcatT, unsigned int* __restrict__ gWB, float* __restrict__ cvec)
{
    int t = blockIdx.x * 256 + threadIdx.x;
    if (t < 13824) {
        // WcatT[c][j] bf16, row-major [288][96]; dword idx = c*48 + j2
        int c = t / 48, j2 = t % 48;
        const float* src = (c < 96) ? Wq : (c < 192) ? Wk : Wv;
        int cc = c % 96;
        float a = src[(2 * j2) * CC + cc];
        float b = src[(2 * j2 + 1) * CC + cc];
        ((unsigned int*)WcatT)[t] = pk2(a, b);
    } else if (t < 13824 + WB_TOT) {
        int i = t - 13824;
        if (i < WB_WPW) {
            int arr = i / WB_ODD;            // 0 = even channels, 1 = odd
            int r = i % WB_ODD;
            int c2 = r / 52, rr = r % 52;
            unsigned int d = 0;
            if (rr < 48) {
                int c = 2 * c2 + arr;
                d = pk2(Wp2[(2 * rr) * CC + c], Wp2[(2 * rr + 1) * CC + c]);
            }
            gWB[i] = d;
        } else {
            int r = i - WB_WPW;
            int g = r / 52, rr = r % 52;
            unsigned int d = 0;
            if (rr < 48) {
                float a = 0.f, b = 0.f;
                for (int c = 0; c < CC; ++c) {
                    float wg = Ww1[c * GG + g];
                    a = fmaf(Wp2[(2 * rr) * CC + c], wg, a);
                    b = fmaf(Wp2[(2 * rr + 1) * CC + c], wg, b);
                }
                d = pk2(a, b);
            }
            gWB[i] = d;
        }
    } else if (t < 13824 + WB_TOT + GG) {
        int g = t - (13824 + WB_TOT);
        float acc = bw1[g];
        for (int c = 0; c < CC; ++c)
            acc = fmaf(bp2[c], Ww1[c * GG + g], acc);
        cvec[g] = acc;
    }
}

// ---------------- kernel 0b: feat -> bf16 ----------------
__global__ __launch_bounds__(256) void fcvt_kernel(
    const float* __restrict__ feat, u16* __restrict__ featB, int total4)
{
    int i = blockIdx.x * 256 + threadIdx.x;
    if (i < total4) {
        float4 v = *(const float4*)(feat + (size_t)i * 4);
        ushort4 o;
        o.x = f2bf(v.x); o.y = f2bf(v.y); o.z = f2bf(v.z); o.w = f2bf(v.w);
        *(ushort4*)(featB + (size_t)i * 4) = o;
    }
}

// ---------------- kernel 1: fused q|k|v MFMA GEMM + epilogue (r6-proven) ----------------
#define SBS 104
__global__ __launch_bounds__(256, 2) void gemm_qkv(
    const u16* __restrict__ featB, const u16* __restrict__ WcatT,
    const float* __restrict__ bq, const float* __restrict__ gq, const float* __restrict__ betaq,
    const float* __restrict__ bk, const float* __restrict__ gk, const float* __restrict__ betak,
    const float* __restrict__ bv, const float* __restrict__ Ww1,
    u16* __restrict__ v_bf, float* __restrict__ KW1, float* __restrict__ qW1, int N)
{
    __shared__ u16 sB[288 * SBS];
    const int t = threadIdx.x;

    for (int i = t; i < 288 * 12; i += 256) {
        int row = i / 12, c8 = i % 12;
        *(float4*)(sB + row * SBS + c8 * 8) = *(const float4*)(WcatT + row * CC + c8 * 8);
    }
    __syncthreads();

    const int wave = t >> 6, lane = t & 63;
    const int m = lane & 15, quad = lane >> 4;
    const int rowbase = blockIdx.x * 64 + wave * 16;

    int arow = rowbase + m;
    if (arow >= N) arow = 0;

    short8 a[3];
    #pragma unroll
    for (int kk = 0; kk < 3; ++kk)
        a[kk] = *(const short8*)(featB + (size_t)arow * CC + kk * 32 + quad * 8);

    f32x4 acc[18];
    #pragma unroll
    for (int nt = 0; nt < 18; ++nt) acc[nt] = (f32x4){0.f, 0.f, 0.f, 0.f};

    #pragma unroll
    for (int kk = 0; kk < 3; ++kk) {
        #pragma unroll
        for (int nt = 0; nt < 18; ++nt) {
            short8 b = *(const short8*)(sB + (nt * 16 + m) * SBS + kk * 32 + quad * 8);
            acc[nt] = __builtin_amdgcn_mfma_f32_16x16x32_bf16(a[kk], b, acc[nt], 0, 0, 0);
        }
    }

    int orow[4];
    #pragma unroll
    for (int i = 0; i < 4; ++i) orow[i] = rowbase + quad * 4 + i;
    const int cloc = m;

    #pragma unroll
    for (int nt6 = 0; nt6 < 6; ++nt6) {
        int c = nt6 * 16 + cloc;
        float bvv = bv[c];
        #pragma unroll
        for (int i = 0; i < 4; ++i)
            if (orow[i] < N)
                v_bf[(size_t)orow[i] * CC + c] = f2bf(acc[12 + nt6][i] + bvv);
    }

    #pragma unroll
    for (int mat = 0; mat < 2; ++mat) {
        const float* bb_ = mat ? bk : bq;
        const float* gg_ = mat ? gk : gq;
        const float* be_ = mat ? betak : betaq;
        float red[4][6];
        #pragma unroll
        for (int i = 0; i < 4; ++i)
            #pragma unroll
            for (int g = 0; g < 6; ++g) red[i][g] = 0.f;

        #pragma unroll
        for (int nt6 = 0; nt6 < 6; ++nt6) {
            int nt = mat * 6 + nt6;
            int c = nt6 * 16 + cloc;
            float bb = bb_[c], sc = gg_[c] * BN_INV, be = be_[c];
            float w1r[6];
            #pragma unroll
            for (int g = 0; g < 6; ++g) w1r[g] = Ww1[c * GG + g];
            #pragma unroll
            for (int i = 0; i < 4; ++i) {
                float act = fmaxf(0.f, fmaf(acc[nt][i] + bb, sc, be));
                #pragma unroll
                for (int g = 0; g < 6; ++g)
                    red[i][g] = fmaf(act, w1r[g], red[i][g]);
            }
        }
        #pragma unroll
        for (int st = 1; st < 16; st <<= 1)
            #pragma unroll
            for (int i = 0; i < 4; ++i)
                #pragma unroll
                for (int g = 0; g < 6; ++g)
                    red[i][g] += __shfl_xor(red[i][g], st);

        float* dst = mat ? KW1 : qW1;
        #pragma unroll
        for (int g = 0; g < 6; ++g)
            if (cloc == g)
                #pragma unroll
                for (int i = 0; i < 4; ++i)
                    if (orow[i] < N)
                        dst[(size_t)orow[i] * 8 + g] = red[i][g];
    }
}

// ---------------- kernel 2: attention v9 — 1-iteration software pipeline ----------------
// Occupancy is pinned at 2 waves/SIMD (natural 172 VGPR; every forced cap spills:
// r1/r3 hint-3 -> 84 regs -> 2.6GB scratch; r4 hint-2 -> 128 regs -> 0.55GB scratch).
// So this version keeps the allocator free and instead removes per-iteration
// latency exposure:
//  - coord[j] / KW1[j] rows for point n+1 loaded into regs at head of iter n
//    (register deps -> compiler inserts exact waits; cover = ~1 full iteration).
//  - v-gather via global_load_lds (per-lane src addr, wave-uniform LDS dest,
//    4B/lane) into a per-wave LDS double buffer; issued at END of iter n,
//    consumed at stage 3 of iter n+1 after one robust s_waitcnt vmcnt(0)
//    placed after stage-2 main (everything outstanding has >=2K cycles cover).
//    Deletes the vpre[16] register array.
//  - center coords folded into stage-1 bias (3 fma) instead of 16 subtracts;
//    sidxx LDS array replaced by __shfl broadcast of the index register.
__global__ __launch_bounds__(256) void attn_kernel(
    const float* __restrict__ coord, const int* __restrict__ ref,
    const float* __restrict__ Wp1, const float* __restrict__ bp1, const float* __restrict__ gp, const float* __restrict__ betap,
    const float* __restrict__ bp2,
    const float* __restrict__ gw, const float* __restrict__ betaw,
    const float* __restrict__ Ww2, const float* __restrict__ bw2,
    const u16* __restrict__ v_bf, const float* __restrict__ KW1, const float* __restrict__ qW1,
    const unsigned int* __restrict__ gWB, const float* __restrict__ cvec,
    float* __restrict__ out, int N)
{
    __shared__ __align__(16) unsigned int sWB[WB_TOT];      // 21216 B
    __shared__ __align__(16) unsigned int shh[4][832];      // 13312 B  h pairs [s*52+L]
    __shared__ __align__(16) uint4 swt[4][SS];              // 1024 B   softmax weights
    __shared__ __align__(16) float sHs[4][600];             // 9600 B   Hsum [g*100+2L]
    __shared__ __align__(16) float4 sposx[4][SS];           // 1024 B   raw neighbor coords
    __shared__ __align__(16) unsigned int svv[4][2][SS*64]; // 32768 B  v dbuf (gather dest)
    // total 78944 B -> 2 blocks/CU (VGPR forces 2 anyway)

    const int t = threadIdx.x;
    for (int i = t; i < WB_TOT; i += 256) sWB[i] = gWB[i];
    __syncthreads();   // only block barrier

    const int w = t >> 6, lane = t & 63;
    const int wid = blockIdx.x * 4 + w;
    unsigned int* shw = shh[w];
    uint4* swtw = swt[w];
    float* sHsw = sHs[w];
    float4* sposw = sposx[w];
    unsigned int* svw = &svv[w][0][0];      // [buf*SS*64 + s*64 + lane]

    const int  L = (lane < 48) ? lane : 47;
    const bool actv = lane < 48;
    const int  cA = 2 * L;
    const int  gL = L >> 3;
    const int  s16 = lane & 15, qq = lane >> 4;

    // BN folded into Wp1: h = relu(sp*(dot+b1) + bt) = relu(dot' + b1')
    const float spA = gp[cA] * BN_INV, spB = gp[cA + 1] * BN_INV;
    const float w1xA = Wp1[cA] * spA, w1yA = Wp1[CC + cA] * spA, w1zA = Wp1[2 * CC + cA] * spA;
    const float w1xB = Wp1[cA + 1] * spB, w1yB = Wp1[CC + cA + 1] * spB, w1zB = Wp1[2 * CC + cA + 1] * spB;
    const float b1A = fmaf(bp1[cA], spA, betap[cA]);
    const float b1B = fmaf(bp1[cA + 1], spB, betap[cA + 1]);
    const float bpA = bp2[cA], bpB = bp2[cA + 1];

    // ---------------- pipeline prologue (point wid) ----------------
    int idx_cur = 0;                 // indices of point n (lane s16 holds neighbor s16)
    if (lane < SS && wid < N) idx_cur = ref[wid * SS + s16];

    float crx = 0.f, cry = 0.f, crz = 0.f;                 // neighbor coords for point n
    float4 kA_next = {0,0,0,0}; float2 kB_next = {0,0};    // KW1 rows for point n
    if (lane < SS && wid < N) {
        crx = coord[idx_cur * 3 + 0];
        cry = coord[idx_cur * 3 + 1];
        crz = coord[idx_cur * 3 + 2];
        const float* kr = KW1 + (size_t)idx_cur * 8;
        kA_next = *(const float4*)kr; kB_next = *(const float2*)(kr + 4);
    }
    // v-gather for point wid into buf 0
    if (wid < N) {
        #pragma unroll
        for (int s = 0; s < SS; ++s) {
            int jj = __shfl(idx_cur, s);
            gldlds4(v_bf + (size_t)jj * CC + cA, svw + s * 64);
        }
    }
    // ref for the following point
    int idx_nn = 0;
    if (lane < SS && wid + TOTW < N) idx_nn = ref[(size_t)(wid + TOTW) * SS + s16];

    int buf = 0;

    for (int n = wid; n < N; n += TOTW) {
        const int nn = n + TOTW, nnn = nn + TOTW;

        // ---- head: commit point-n state, issue point-(n+1) loads ----
        float4 kAv = kA_next; float2 kBv = kB_next;   // rotate k rows (point n)
        if (lane < SS)
            sposw[s16] = make_float4(crx, cry, crz, 0.f);   // raw coords of n's neighbors
        if (lane < SS && nn < N) {
            crx = coord[idx_nn * 3 + 0];
            cry = coord[idx_nn * 3 + 1];
            crz = coord[idx_nn * 3 + 2];
            const float* kr = KW1 + (size_t)idx_nn * 8;
            kA_next = *(const float4*)kr; kB_next = *(const float2*)(kr + 4);
        }
        int idx_fut = 0;
        if (lane < SS && nnn < N) idx_fut = ref[(size_t)nnn * SS + s16];

        // uniform q-row + center (n is wave-uniform -> scalar loads)
        float qc[GG];
        {
            int nu = __builtin_amdgcn_readfirstlane(n);
            const float* qr = qW1 + (size_t)nu * 8;
            #pragma unroll
            for (int g = 0; g < GG; ++g)
                qc[g] = rfl_f(cvec[g] - qr[g]);
        }
        const float cnx = coord[n * 3 + 0], cny = coord[n * 3 + 1], cnz = coord[n * 3 + 2];
        // center folded into stage-1 bias: h = cj.x*w1x + cj.y*w1y + cj.z*w1z + (b1 - cn.w1)
        const float b1An = b1A - (cnx * w1xA + cny * w1yA + cnz * w1zA);
        const float b1Bn = b1B - (cnx * w1xB + cny * w1yB + cnz * w1zB);

        // ---- stage 1: h = relu(pos@Wp1' + b1') -> packed bf16 pairs ----
        if (actv) {
            #pragma unroll
            for (int s = 0; s < SS; ++s) {
                float4 P = sposw[s];                 // broadcast b128 (raw coords)
                float hA = fmaxf(0.f, fmaf(P.x, w1xA, fmaf(P.y, w1yA, fmaf(P.z, w1zA, b1An))));
                float hB = fmaxf(0.f, fmaf(P.x, w1xB, fmaf(P.y, w1yB, fmaf(P.z, w1zB, b1Bn))));
                shw[s * 52 + L] = pk2(hA, hB);
            }
        }

        // ---- stage 2 main: logits, 8-channel chunks ----
        float acc[GG];
        {
            const unsigned int* hrow = shw + 52 * s16 + 12 * qq;
            const unsigned int* wbase = sWB + WB_WPW + 12 * qq;
            #pragma unroll
            for (int g = 0; g < GG; ++g) acc[g] = 0.f;
            #pragma unroll
            for (int c3 = 0; c3 < 3; ++c3) {
                float hg[8];
                bf8x(*(const uint4*)(hrow + 4 * c3), hg);
                #pragma unroll
                for (int g = 0; g < GG; ++g) {
                    float wg[8];
                    bf8x(*(const uint4*)(wbase + g * 52 + 4 * c3), wg);
                    float a = acc[g];
                    #pragma unroll
                    for (int u = 0; u < 8; ++u)
                        a = fmaf(hg[u], wg[u], a);
                    acc[g] = a;
                }
            }
            #pragma unroll
            for (int g = 0; g < GG; ++g) {
                acc[g] += __shfl_xor(acc[g], 16);
                acc[g] += __shfl_xor(acc[g], 32);
            }
        }

        // drain all outstanding VMEM: v[buf] (issued last iter end, ~3K cycles ago)
        // and this iter's head loads (~2K cycles ago). No counted-vmcnt fragility.
        asm volatile("s_waitcnt vmcnt(0)" ::: "memory");

        // ---- stage 2 epilogue: softmax weights (lanes < 16) ----
        if (lane < SS) {
            float tv[GG];
            tv[0] = acc[0] + kAv.x + qc[0];
            tv[1] = acc[1] + kAv.y + qc[1];
            tv[2] = acc[2] + kAv.z + qc[2];
            tv[3] = acc[3] + kAv.w + qc[3];
            tv[4] = acc[4] + kBv.x + qc[4];
            tv[5] = acc[5] + kBv.y + qc[5];
            float a6[GG];
            #pragma unroll
            for (int g = 0; g < GG; ++g)
                a6[g] = fmaxf(0.f, fmaf(tv[g], gw[g] * BN_INV, betaw[g]));
            float e[GG];
            #pragma unroll
            for (int gg2 = 0; gg2 < GG; ++gg2) {
                float lv = bw2[gg2];
                #pragma unroll
                for (int g2 = 0; g2 < GG; ++g2)
                    lv = fmaf(a6[g2], Ww2[g2 * GG + gg2], lv);
                e[gg2] = __expf(lv);
            }
            float wgt[GG];
            #pragma unroll
            for (int g = 0; g < GG; ++g) {
                float ssum = e[g];
                ssum += __shfl_xor(ssum, 1);
                ssum += __shfl_xor(ssum, 2);
                ssum += __shfl_xor(ssum, 4);
                ssum += __shfl_xor(ssum, 8);
                wgt[g] = e[g] / ssum;
            }
            uint4 wt;
            wt.x = pk2(wgt[0], wgt[1]);
            wt.y = pk2(wgt[2], wgt[3]);
            wt.z = pk2(wgt[4], wgt[5]);
            wt.w = 0u;
            swtw[s16] = wt;
        }

        // ---- stage 3+4: Hsum + v-part fused (v from LDS gather buffer) ----
        float accA = bpA, accB = bpB;
        {
            const unsigned int* svb = svw + buf * (SS * 64);
            float hsA[GG] = {0.f,0.f,0.f,0.f,0.f,0.f};
            float hsB[GG] = {0.f,0.f,0.f,0.f,0.f,0.f};
            #pragma unroll
            for (int s = 0; s < SS; ++s) {
                uint4 wt = swtw[s];                  // broadcast b128
                float2 w01 = bf2x(wt.x), w23 = bf2x(wt.y), w45 = bf2x(wt.z);
                float2 h2 = bf2x(shw[s * 52 + L]);
                hsA[0] = fmaf(w01.x, h2.x, hsA[0]); hsB[0] = fmaf(w01.x, h2.y, hsB[0]);
                hsA[1] = fmaf(w01.y, h2.x, hsA[1]); hsB[1] = fmaf(w01.y, h2.y, hsB[1]);
                hsA[2] = fmaf(w23.x, h2.x, hsA[2]); hsB[2] = fmaf(w23.x, h2.y, hsB[2]);
                hsA[3] = fmaf(w23.y, h2.x, hsA[3]); hsB[3] = fmaf(w23.y, h2.y, hsB[3]);
                hsA[4] = fmaf(w45.x, h2.x, hsA[4]); hsB[4] = fmaf(w45.x, h2.y, hsB[4]);
                hsA[5] = fmaf(w45.y, h2.x, hsA[5]); hsB[5] = fmaf(w45.y, h2.y, hsB[5]);
                float wsel = (gL < 2) ? (gL == 0 ? w01.x : w01.y)
                           : (gL < 4) ? (gL == 2 ? w23.x : w23.y)
                                      : (gL == 4 ? w45.x : w45.y);
                float2 v2 = bf2x(svb[s * 64 + lane]);   // 64 consec dwords: conflict-free
                accA = fmaf(v2.x, wsel, accA);
                accB = fmaf(v2.y, wsel, accB);
            }
            if (actv) {
                #pragma unroll
                for (int g = 0; g < GG; ++g)
                    *(float2*)(sHsw + g * 100 + cA) = make_float2(hsA[g], hsB[g]);
            }
        }

        // ---- stage 5: out = v-part + Hsum[gL] @ Wp2 cols ----
        if (actv) {
            const float* hrg = sHsw + gL * 100;
            const unsigned int* wrE = sWB + L * 52;            // even channel cA
            const unsigned int* wrO = sWB + WB_ODD + L * 52;   // odd channel cA+1
            #pragma unroll
            for (int u = 0; u < 12; ++u) {
                float4 hb0 = *(const float4*)(hrg + 8 * u);
                float4 hb1 = *(const float4*)(hrg + 8 * u + 4);
                float we[8], wo[8];
                bf8x(*(const uint4*)(wrE + 4 * u), we);
                bf8x(*(const uint4*)(wrO + 4 * u), wo);
                accA = fmaf(hb0.x, we[0], accA); accB = fmaf(hb0.x, wo[0], accB);
                accA = fmaf(hb0.y, we[1], accA); accB = fmaf(hb0.y, wo[1], accB);
                accA = fmaf(hb0.z, we[2], accA); accB = fmaf(hb0.z, wo[2], accB);
                accA = fmaf(hb0.w, we[3], accA); accB = fmaf(hb0.w, wo[3], accB);
                accA = fmaf(hb1.x, we[4], accA); accB = fmaf(hb1.x, wo[4], accB);
                accA = fmaf(hb1.y, we[5], accA); accB = fmaf(hb1.y, wo[5], accB);
                accA = fmaf(hb1.z, we[6], accA); accB = fmaf(hb1.z, wo[6], accB);
                accA = fmaf(hb1.w, we[7], accA); accB = fmaf(hb1.w, wo[7], accB);
            }
            *(float2*)(out + (size_t)n * CC + cA) = make_float2(accA, accB);
        }

        // ---- issue v-gather for point n+1 into the other buffer ----
        if (nn < N) {
            unsigned int* dst = svw + (buf ^ 1) * (SS * 64);
            #pragma unroll
            for (int s = 0; s < SS; ++s) {
                int jj = __shfl(idx_nn, s);
                gldlds4(v_bf + (size_t)jj * CC + cA, dst + s * 64);
            }
        }
        idx_nn = idx_fut;
        buf ^= 1;
    }
}

extern "C" void kernel_launch(void* const* d_in, const int* in_sizes, int n_in,
                              void* d_out, int out_size, void* d_ws, size_t ws_size,
                              hipStream_t stream) {
    const float* feat  = (const float*)d_in[0];
    const float* coord = (const float*)d_in[1];
    const int*   ref   = (const int*)d_in[2];
    const float* Wq = (const float*)d_in[3],  *bq = (const float*)d_in[4],  *gq = (const float*)d_in[5],  *betaq = (const float*)d_in[6];
    const float* Wk = (const float*)d_in[7],  *bk = (const float*)d_in[8],  *gk = (const float*)d_in[9],  *betak = (const float*)d_in[10];
    const float* Wv = (const float*)d_in[11], *bv = (const float*)d_in[12];
    const float* Wp1 = (const float*)d_in[13], *bp1 = (const float*)d_in[14], *gp = (const float*)d_in[15], *betap = (const float*)d_in[16];
    const float* Wp2 = (const float*)d_in[17], *bp2 = (const float*)d_in[18];
    const float* Ww1 = (const float*)d_in[19], *bw1 = (const float*)d_in[20], *gw = (const float*)d_in[21], *betaw = (const float*)d_in[22];
    const float* Ww2 = (const float*)d_in[23], *bw2 = (const float*)d_in[24];

    const int N = in_sizes[0] / CC;   // 50000

    // workspace (~23 MB)
    float* wsf = (float*)d_ws;
    float* KW1 = wsf;                                  // N*8 f32
    float* qW1 = KW1 + (size_t)N * 8;                  // N*8 f32
    float* cvec = qW1 + (size_t)N * 8;                 // 6 (pad 32)
    unsigned int* gWB = (unsigned int*)(cvec + 32);    // 5304 (pad 5312)
    u16* WcatT = (u16*)(gWB + 5312);                   // 288*96 bf16
    u16* featB = WcatT + 288 * CC;                     // N*96 bf16
    u16* v_bf = featB + (size_t)N * CC;                // N*96 bf16

    const int prep_total = 13824 + WB_TOT + GG;
    prep_kernel<<<dim3((prep_total + 255) / 256), dim3(256), 0, stream>>>(
        Wq, Wk, Wv, Wp2, Ww1, bp2, bw1, WcatT, gWB, cvec);

    const int total4 = N * CC / 4;
    fcvt_kernel<<<dim3((total4 + 255) / 256), dim3(256), 0, stream>>>(feat, featB, total4);

    gemm_qkv<<<dim3((N + 63) / 64), dim3(256), 0, stream>>>(
        featB, WcatT, bq, gq, betaq, bk, gk, betak, bv, Ww1,
        v_bf, KW1, qW1, N);

    attn_kernel<<<dim3(ABLK), dim3(256), 0, stream>>>(
        coord, ref, Wp1, bp1, gp, betap, bp2, gw, betaw, Ww2, bw2,
        v_bf, KW1, qW1, gWB, cvec, (float*)d_out, N);
}

// Round 6
// 424.663 us; speedup vs baseline: 2.3102x; 1.0823x over previous
//
#include <hip/hip_runtime.h>

typedef unsigned short u16;
typedef __attribute__((ext_vector_type(8))) short short8;   // 8 bf16 (4 VGPRs)
typedef __attribute__((ext_vector_type(4))) float f32x4;

__device__ __forceinline__ u16 f2bf(float f) {
    unsigned int x = __float_as_uint(f);
    unsigned int r = x + 0x7fffu + ((x >> 16) & 1u);
    return (u16)(r >> 16);
}
__device__ __forceinline__ unsigned int pk2(float lo, float hi) {
    return ((unsigned int)f2bf(hi) << 16) | (unsigned int)f2bf(lo);
}
__device__ __forceinline__ float2 bf2x(unsigned int d) {
    float2 r;
    r.x = __uint_as_float(d << 16);
    r.y = __uint_as_float(d & 0xffff0000u);
    return r;
}
__device__ __forceinline__ void bf8x(uint4 v, float* o) {
    float2 a = bf2x(v.x); o[0] = a.x; o[1] = a.y;
    float2 b = bf2x(v.y); o[2] = b.x; o[3] = b.y;
    float2 c = bf2x(v.z); o[4] = c.x; o[5] = c.y;
    float2 d = bf2x(v.w); o[6] = d.x; o[7] = d.y;
}
__device__ __forceinline__ float rfl_f(float x) {
    return __uint_as_float(__builtin_amdgcn_readfirstlane(__float_as_uint(x)));
}

#define CC 96
#define SS 16
#define GG 6
#define BN_INV 0.99999500003749969f  // 1/sqrt(1+1e-5)
#define ABLK 768                     // 3 blocks/CU target (VGPR ~148 natural, LDS 46.6KB)
#define TOTW (ABLK * 4)

// gWB image (dwords, bf16 pairs): [0..2495] Wp2 even cols (row c2=channel/2,
// stride 52 dw, 48 used), [2496..4991] Wp2 odd cols, [4992..5303] Wpw rows.
#define WB_ODD 2496
#define WB_WPW 4992
#define WB_TOT 5304

// ---------------- kernel 0: prep (weights repack + tiny precompute) ----------------
__global__ __launch_bounds__(256) void prep_kernel(
    const float* __restrict__ Wq, const float* __restrict__ Wk, const float* __restrict__ Wv,
    const float* __restrict__ Wp2, const float* __restrict__ Ww1,
    const float* __restrict__ bp2, const float* __restrict__ bw1,
    u16* __restrict__ WcatT, unsigned int* __restrict__ gWB, float* __restrict__ cvec)
{
    int t = blockIdx.x * 256 + threadIdx.x;
    if (t < 13824) {
        // WcatT[c][j] bf16, row-major [288][96]; dword idx = c*48 + j2
        int c = t / 48, j2 = t % 48;
        const float* src = (c < 96) ? Wq : (c < 192) ? Wk : Wv;
        int cc = c % 96;
        float a = src[(2 * j2) * CC + cc];
        float b = src[(2 * j2 + 1) * CC + cc];
        ((unsigned int*)WcatT)[t] = pk2(a, b);
    } else if (t < 13824 + WB_TOT) {
        int i = t - 13824;
        if (i < WB_WPW) {
            int arr = i / WB_ODD;            // 0 = even channels, 1 = odd
            int r = i % WB_ODD;
            int c2 = r / 52, rr = r % 52;
            unsigned int d = 0;
            if (rr < 48) {
                int c = 2 * c2 + arr;
                d = pk2(Wp2[(2 * rr) * CC + c], Wp2[(2 * rr + 1) * CC + c]);
            }
            gWB[i] = d;
        } else {
            int r = i - WB_WPW;
            int g = r / 52, rr = r % 52;
            unsigned int d = 0;
            if (rr < 48) {
                float a = 0.f, b = 0.f;
                for (int c = 0; c < CC; ++c) {
                    float wg = Ww1[c * GG + g];
                    a = fmaf(Wp2[(2 * rr) * CC + c], wg, a);
                    b = fmaf(Wp2[(2 * rr + 1) * CC + c], wg, b);
                }
                d = pk2(a, b);
            }
            gWB[i] = d;
        }
    } else if (t < 13824 + WB_TOT + GG) {
        int g = t - (13824 + WB_TOT);
        float acc = bw1[g];
        for (int c = 0; c < CC; ++c)
            acc = fmaf(bp2[c], Ww1[c * GG + g], acc);
        cvec[g] = acc;
    }
}

// ---------------- kernel 0b: feat -> bf16 ----------------
__global__ __launch_bounds__(256) void fcvt_kernel(
    const float* __restrict__ feat, u16* __restrict__ featB, int total4)
{
    int i = blockIdx.x * 256 + threadIdx.x;
    if (i < total4) {
        float4 v = *(const float4*)(feat + (size_t)i * 4);
        ushort4 o;
        o.x = f2bf(v.x); o.y = f2bf(v.y); o.z = f2bf(v.z); o.w = f2bf(v.w);
        *(ushort4*)(featB + (size_t)i * 4) = o;
    }
}

// ---------------- kernel 1: fused q|k|v MFMA GEMM + epilogue (r6-proven) ----------------
#define SBS 104
__global__ __launch_bounds__(256, 2) void gemm_qkv(
    const u16* __restrict__ featB, const u16* __restrict__ WcatT,
    const float* __restrict__ bq, const float* __restrict__ gq, const float* __restrict__ betaq,
    const float* __restrict__ bk, const float* __restrict__ gk, const float* __restrict__ betak,
    const float* __restrict__ bv, const float* __restrict__ Ww1,
    u16* __restrict__ v_bf, float* __restrict__ KW1, float* __restrict__ qW1, int N)
{
    __shared__ u16 sB[288 * SBS];
    const int t = threadIdx.x;

    for (int i = t; i < 288 * 12; i += 256) {
        int row = i / 12, c8 = i % 12;
        *(float4*)(sB + row * SBS + c8 * 8) = *(const float4*)(WcatT + row * CC + c8 * 8);
    }
    __syncthreads();

    const int wave = t >> 6, lane = t & 63;
    const int m = lane & 15, quad = lane >> 4;
    const int rowbase = blockIdx.x * 64 + wave * 16;

    int arow = rowbase + m;
    if (arow >= N) arow = 0;

    short8 a[3];
    #pragma unroll
    for (int kk = 0; kk < 3; ++kk)
        a[kk] = *(const short8*)(featB + (size_t)arow * CC + kk * 32 + quad * 8);

    f32x4 acc[18];
    #pragma unroll
    for (int nt = 0; nt < 18; ++nt) acc[nt] = (f32x4){0.f, 0.f, 0.f, 0.f};

    #pragma unroll
    for (int kk = 0; kk < 3; ++kk) {
        #pragma unroll
        for (int nt = 0; nt < 18; ++nt) {
            short8 b = *(const short8*)(sB + (nt * 16 + m) * SBS + kk * 32 + quad * 8);
            acc[nt] = __builtin_amdgcn_mfma_f32_16x16x32_bf16(a[kk], b, acc[nt], 0, 0, 0);
        }
    }

    int orow[4];
    #pragma unroll
    for (int i = 0; i < 4; ++i) orow[i] = rowbase + quad * 4 + i;
    const int cloc = m;

    #pragma unroll
    for (int nt6 = 0; nt6 < 6; ++nt6) {
        int c = nt6 * 16 + cloc;
        float bvv = bv[c];
        #pragma unroll
        for (int i = 0; i < 4; ++i)
            if (orow[i] < N)
                v_bf[(size_t)orow[i] * CC + c] = f2bf(acc[12 + nt6][i] + bvv);
    }

    #pragma unroll
    for (int mat = 0; mat < 2; ++mat) {
        const float* bb_ = mat ? bk : bq;
        const float* gg_ = mat ? gk : gq;
        const float* be_ = mat ? betak : betaq;
        float red[4][6];
        #pragma unroll
        for (int i = 0; i < 4; ++i)
            #pragma unroll
            for (int g = 0; g < 6; ++g) red[i][g] = 0.f;

        #pragma unroll
        for (int nt6 = 0; nt6 < 6; ++nt6) {
            int nt = mat * 6 + nt6;
            int c = nt6 * 16 + cloc;
            float bb = bb_[c], sc = gg_[c] * BN_INV, be = be_[c];
            float w1r[6];
            #pragma unroll
            for (int g = 0; g < 6; ++g) w1r[g] = Ww1[c * GG + g];
            #pragma unroll
            for (int i = 0; i < 4; ++i) {
                float act = fmaxf(0.f, fmaf(acc[nt][i] + bb, sc, be));
                #pragma unroll
                for (int g = 0; g < 6; ++g)
                    red[i][g] = fmaf(act, w1r[g], red[i][g]);
            }
        }
        #pragma unroll
        for (int st = 1; st < 16; st <<= 1)
            #pragma unroll
            for (int i = 0; i < 4; ++i)
                #pragma unroll
                for (int g = 0; g < 6; ++g)
                    red[i][g] += __shfl_xor(red[i][g], st);

        float* dst = mat ? KW1 : qW1;
        #pragma unroll
        for (int g = 0; g < 6; ++g)
            if (cloc == g)
                #pragma unroll
                for (int i = 0; i < 4; ++i)
                    if (orow[i] < N)
                        dst[(size_t)orow[i] * 8 + g] = red[i][g];
    }
}

// ---------------- kernel 2: attention v10 — natural 3-tier: r2 structure + chunked stage 2 ----------------
// Register-pressure history: natural demand was 172 (r0/r2, 2 waves/SIMD); every
// forced cap spilled (hint-3 -> 84 regs/2.6GB scratch; hint-2 -> 128/0.55GB).
// r5 PROVED natural demand drops to 132 with: chunked stage-2 (hg[8]+wg[8]
// transients) + scalarized q-row + no vpre[16] array. But r5's LDS v-buffer
// (79.4KB) capped residency at 2 blocks/CU, wasting the VGPR win.
// v10 = r2's proven structure (v-gather into REGISTERS after stage-2 main,
// 46.6KB LDS, no asm drains) + the chunked stage-2. Estimated natural VGPR
// ~148 (132 + vpre 16) <= 168 -> 3 waves/SIMD; LDS 46.6KB*3 = 139.8KB < 160KB
// -> 3 blocks/CU. Both constraints clear the 3-occupancy tier NATURALLY.
// ABLK=768 == 3 blocks/CU exactly.
__global__ __launch_bounds__(256) void attn_kernel(
    const float* __restrict__ coord, const int* __restrict__ ref,
    const float* __restrict__ Wp1, const float* __restrict__ bp1, const float* __restrict__ gp, const float* __restrict__ betap,
    const float* __restrict__ bp2,
    const float* __restrict__ gw, const float* __restrict__ betaw,
    const float* __restrict__ Ww2, const float* __restrict__ bw2,
    const u16* __restrict__ v_bf, const float* __restrict__ KW1, const float* __restrict__ qW1,
    const unsigned int* __restrict__ gWB, const float* __restrict__ cvec,
    float* __restrict__ out, int N)
{
    __shared__ __align__(16) unsigned int sWB[WB_TOT];  // 21216 B
    __shared__ __align__(16) unsigned int shh[4][832];  // h bf16 pairs [s*52 + L]
    __shared__ __align__(16) uint4 swt[4][SS];          // packed softmax weights per s
    __shared__ __align__(16) float sHs[4][600];         // Hsum fp32 [g*100 + 2L]
    __shared__ __align__(16) float4 sposx[4][SS];
    __shared__ int sidxx[4][SS];

    const int t = threadIdx.x;
    for (int i = t; i < WB_TOT; i += 256) sWB[i] = gWB[i];
    __syncthreads();   // only block barrier

    const int w = t >> 6, lane = t & 63;
    const int wid = blockIdx.x * 4 + w;
    unsigned int* shw = shh[w];
    uint4* swtw = swt[w];
    float* sHsw = sHs[w];
    float4* sposw = sposx[w];
    int* sidxw = sidxx[w];

    const int  L = (lane < 48) ? lane : 47;
    const bool actv = lane < 48;
    const int  cA = 2 * L;
    const int  gL = L >> 3;
    const int  s16 = lane & 15, qq = lane >> 4;

    // BN folded into Wp1: h = relu(sp*(dot+b1) + bt) = relu(dot' + b1')
    const float spA = gp[cA] * BN_INV, spB = gp[cA + 1] * BN_INV;
    const float w1xA = Wp1[cA] * spA, w1yA = Wp1[CC + cA] * spA, w1zA = Wp1[2 * CC + cA] * spA;
    const float w1xB = Wp1[cA + 1] * spB, w1yB = Wp1[CC + cA + 1] * spB, w1zB = Wp1[2 * CC + cA + 1] * spB;
    const float b1A = fmaf(bp1[cA], spA, betap[cA]);
    const float b1B = fmaf(bp1[cA + 1], spB, betap[cA + 1]);
    const float bpA = bp2[cA], bpB = bp2[cA + 1];

    // prefetched ref indices for the upcoming iteration
    int idxreg = 0;
    if (lane < SS && wid < N) idxreg = ref[wid * SS + s16];

    for (int n = wid; n < N; n += TOTW) {
        // ---- head: indices, pos, k-row gather ----
        if (lane < SS) sidxw[s16] = idxreg;
        float4 kAv = {0,0,0,0}; float2 kBv = {0,0};
        if (lane < SS) {
            int j = idxreg;
            float4 P;
            P.x = coord[j * 3 + 0] - coord[n * 3 + 0];
            P.y = coord[j * 3 + 1] - coord[n * 3 + 1];
            P.z = coord[j * 3 + 2] - coord[n * 3 + 2];
            P.w = 0.f;
            sposw[s16] = P;
            const float* kr = KW1 + (size_t)idxreg * 8;
            kAv = *(const float4*)kr; kBv = *(const float2*)(kr + 4);
        }
        // uniform q-row: fold cvec - q into SGPRs (n is wave-uniform)
        float qc[GG];
        {
            int nu = __builtin_amdgcn_readfirstlane(n);
            const float* qr = qW1 + (size_t)nu * 8;
            #pragma unroll
            for (int g = 0; g < GG; ++g)
                qc[g] = rfl_f(cvec[g] - qr[g]);
        }
        // issue next iteration's ref load now; result consumed next iteration
        {
            int nn = n + TOTW;
            if (lane < SS && nn < N) idxreg = ref[nn * SS + s16];
        }

        // ---- stage 1: h = relu(pos@Wp1' + b1') -> packed bf16 pairs ----
        if (actv) {
            #pragma unroll
            for (int s = 0; s < SS; ++s) {
                float4 P = sposw[s];                 // broadcast b128
                float hA = fmaxf(0.f, fmaf(P.x, w1xA, fmaf(P.y, w1yA, fmaf(P.z, w1zA, b1A))));
                float hB = fmaxf(0.f, fmaf(P.x, w1xB, fmaf(P.y, w1yB, fmaf(P.z, w1zB, b1B))));
                shw[s * 52 + L] = pk2(hA, hB);
            }
        }

        // ---- stage 2 main: logits, 8-channel chunks (low register peak) ----
        float acc[GG];
        {
            const unsigned int* hrow = shw + 52 * s16 + 12 * qq;
            const unsigned int* wbase = sWB + WB_WPW + 12 * qq;
            #pragma unroll
            for (int g = 0; g < GG; ++g) acc[g] = 0.f;
            #pragma unroll
            for (int c3 = 0; c3 < 3; ++c3) {
                float hg[8];
                bf8x(*(const uint4*)(hrow + 4 * c3), hg);
                #pragma unroll
                for (int g = 0; g < GG; ++g) {
                    float wg[8];
                    bf8x(*(const uint4*)(wbase + g * 52 + 4 * c3), wg);
                    float a = acc[g];
                    #pragma unroll
                    for (int u = 0; u < 8; ++u)
                        a = fmaf(hg[u], wg[u], a);
                    acc[g] = a;
                }
            }
            #pragma unroll
            for (int g = 0; g < GG; ++g) {
                acc[g] += __shfl_xor(acc[g], 16);
                acc[g] += __shfl_xor(acc[g], 32);
            }
        }

        // ---- v gather (kept out of the stage-2 register peak) ----
        unsigned int vpre[SS];
        #pragma unroll
        for (int s = 0; s < SS; ++s) {
            int jj = sidxw[s];                       // wave-private, in-order DS
            vpre[s] = *(const unsigned int*)(v_bf + (size_t)jj * CC + cA);
        }

        // ---- stage 2 epilogue: softmax weights (lanes < 16) ----
        if (lane < SS) {
            float tv[GG];
            tv[0] = acc[0] + kAv.x + qc[0];
            tv[1] = acc[1] + kAv.y + qc[1];
            tv[2] = acc[2] + kAv.z + qc[2];
            tv[3] = acc[3] + kAv.w + qc[3];
            tv[4] = acc[4] + kBv.x + qc[4];
            tv[5] = acc[5] + kBv.y + qc[5];
            float a6[GG];
            #pragma unroll
            for (int g = 0; g < GG; ++g)
                a6[g] = fmaxf(0.f, fmaf(tv[g], gw[g] * BN_INV, betaw[g]));
            float e[GG];
            #pragma unroll
            for (int gg2 = 0; gg2 < GG; ++gg2) {
                float lv = bw2[gg2];
                #pragma unroll
                for (int g2 = 0; g2 < GG; ++g2)
                    lv = fmaf(a6[g2], Ww2[g2 * GG + gg2], lv);
                e[gg2] = __expf(lv);
            }
            float wgt[GG];
            #pragma unroll
            for (int g = 0; g < GG; ++g) {
                float ssum = e[g];
                ssum += __shfl_xor(ssum, 1);
                ssum += __shfl_xor(ssum, 2);
                ssum += __shfl_xor(ssum, 4);
                ssum += __shfl_xor(ssum, 8);
                wgt[g] = e[g] / ssum;
            }
            uint4 wt;
            wt.x = pk2(wgt[0], wgt[1]);
            wt.y = pk2(wgt[2], wgt[3]);
            wt.z = pk2(wgt[4], wgt[5]);
            wt.w = 0u;
            swtw[s16] = wt;
        }

        // ---- stage 3+4: Hsum + v-part fused ----
        float accA = bpA, accB = bpB;
        {
            float hsA[GG] = {0.f,0.f,0.f,0.f,0.f,0.f};
            float hsB[GG] = {0.f,0.f,0.f,0.f,0.f,0.f};
            #pragma unroll
            for (int s = 0; s < SS; ++s) {
                uint4 wt = swtw[s];                  // broadcast b128
                float2 w01 = bf2x(wt.x), w23 = bf2x(wt.y), w45 = bf2x(wt.z);
                float2 h2 = bf2x(shw[s * 52 + L]);
                hsA[0] = fmaf(w01.x, h2.x, hsA[0]); hsB[0] = fmaf(w01.x, h2.y, hsB[0]);
                hsA[1] = fmaf(w01.y, h2.x, hsA[1]); hsB[1] = fmaf(w01.y, h2.y, hsB[1]);
                hsA[2] = fmaf(w23.x, h2.x, hsA[2]); hsB[2] = fmaf(w23.x, h2.y, hsB[2]);
                hsA[3] = fmaf(w23.y, h2.x, hsA[3]); hsB[3] = fmaf(w23.y, h2.y, hsB[3]);
                hsA[4] = fmaf(w45.x, h2.x, hsA[4]); hsB[4] = fmaf(w45.x, h2.y, hsB[4]);
                hsA[5] = fmaf(w45.y, h2.x, hsA[5]); hsB[5] = fmaf(w45.y, h2.y, hsB[5]);
                float wsel = (gL < 2) ? (gL == 0 ? w01.x : w01.y)
                           : (gL < 4) ? (gL == 2 ? w23.x : w23.y)
                                      : (gL == 4 ? w45.x : w45.y);
                float2 v2 = bf2x(vpre[s]);
                accA = fmaf(v2.x, wsel, accA);
                accB = fmaf(v2.y, wsel, accB);
            }
            if (actv) {
                #pragma unroll
                for (int g = 0; g < GG; ++g)
                    *(float2*)(sHsw + g * 100 + cA) = make_float2(hsA[g], hsB[g]);
            }
        }

        // ---- stage 5: out = v-part + Hsum[gL] @ Wp2 cols ----
        if (actv) {
            const float* hrg = sHsw + gL * 100;
            const unsigned int* wrE = sWB + L * 52;            // even channel cA
            const unsigned int* wrO = sWB + WB_ODD + L * 52;   // odd channel cA+1
            #pragma unroll
            for (int u = 0; u < 12; ++u) {
                float4 hb0 = *(const float4*)(hrg + 8 * u);
                float4 hb1 = *(const float4*)(hrg + 8 * u + 4);
                float we[8], wo[8];
                bf8x(*(const uint4*)(wrE + 4 * u), we);
                bf8x(*(const uint4*)(wrO + 4 * u), wo);
                accA = fmaf(hb0.x, we[0], accA); accB = fmaf(hb0.x, wo[0], accB);
                accA = fmaf(hb0.y, we[1], accA); accB = fmaf(hb0.y, wo[1], accB);
                accA = fmaf(hb0.z, we[2], accA); accB = fmaf(hb0.z, wo[2], accB);
                accA = fmaf(hb0.w, we[3], accA); accB = fmaf(hb0.w, wo[3], accB);
                accA = fmaf(hb1.x, we[4], accA); accB = fmaf(hb1.x, wo[4], accB);
                accA = fmaf(hb1.y, we[5], accA); accB = fmaf(hb1.y, wo[5], accB);
                accA = fmaf(hb1.z, we[6], accA); accB = fmaf(hb1.z, wo[6], accB);
                accA = fmaf(hb1.w, we[7], accA); accB = fmaf(hb1.w, wo[7], accB);
            }
            *(float2*)(out + (size_t)n * CC + cA) = make_float2(accA, accB);
        }
    }
}

extern "C" void kernel_launch(void* const* d_in, const int* in_sizes, int n_in,
                              void* d_out, int out_size, void* d_ws, size_t ws_size,
                              hipStream_t stream) {
    const float* feat  = (const float*)d_in[0];
    const float* coord = (const float*)d_in[1];
    const int*   ref   = (const int*)d_in[2];
    const float* Wq = (const float*)d_in[3],  *bq = (const float*)d_in[4],  *gq = (const float*)d_in[5],  *betaq = (const float*)d_in[6];
    const float* Wk = (const float*)d_in[7],  *bk = (const float*)d_in[8],  *gk = (const float*)d_in[9],  *betak = (const float*)d_in[10];
    const float* Wv = (const float*)d_in[11], *bv = (const float*)d_in[12];
    const float* Wp1 = (const float*)d_in[13], *bp1 = (const float*)d_in[14], *gp = (const float*)d_in[15], *betap = (const float*)d_in[16];
    const float* Wp2 = (const float*)d_in[17], *bp2 = (const float*)d_in[18];
    const float* Ww1 = (const float*)d_in[19], *bw1 = (const float*)d_in[20], *gw = (const float*)d_in[21], *betaw = (const float*)d_in[22];
    const float* Ww2 = (const float*)d_in[23], *bw2 = (const float*)d_in[24];

    const int N = in_sizes[0] / CC;   // 50000

    // workspace (~23 MB)
    float* wsf = (float*)d_ws;
    float* KW1 = wsf;                                  // N*8 f32
    float* qW1 = KW1 + (size_t)N * 8;                  // N*8 f32
    float* cvec = qW1 + (size_t)N * 8;                 // 6 (pad 32)
    unsigned int* gWB = (unsigned int*)(cvec + 32);    // 5304 (pad 5312)
    u16* WcatT = (u16*)(gWB + 5312);                   // 288*96 bf16
    u16* featB = WcatT + 288 * CC;                     // N*96 bf16
    u16* v_bf = featB + (size_t)N * CC;                // N*96 bf16

    const int prep_total = 13824 + WB_TOT + GG;
    prep_kernel<<<dim3((prep_total + 255) / 256), dim3(256), 0, stream>>>(
        Wq, Wk, Wv, Wp2, Ww1, bp2, bw1, WcatT, gWB, cvec);

    const int total4 = N * CC / 4;
    fcvt_kernel<<<dim3((total4 + 255) / 256), dim3(256), 0, stream>>>(feat, featB, total4);

    gemm_qkv<<<dim3((N + 63) / 64), dim3(256), 0, stream>>>(
        featB, WcatT, bq, gq, betaq, bk, gk, betak, bv, Ww1,
        v_bf, KW1, qW1, N);

    attn_kernel<<<dim3(ABLK), dim3(256), 0, stream>>>(
        coord, ref, Wp1, bp1, gp, betap, bp2, gw, betaw, Ww2, bw2,
        v_bf, KW1, qW1, gWB, cvec, (float*)d_out, N);
}

// Round 7
// 387.427 us; speedup vs baseline: 2.5323x; 1.0961x over previous
//
#include <hip/hip_runtime.h>

typedef unsigned short u16;
typedef __attribute__((ext_vector_type(8))) short short8;   // 8 bf16 (4 VGPRs)
typedef __attribute__((ext_vector_type(4))) float f32x4;

__device__ __forceinline__ u16 f2bf(float f) {
    unsigned int x = __float_as_uint(f);
    unsigned int r = x + 0x7fffu + ((x >> 16) & 1u);
    return (u16)(r >> 16);
}
__device__ __forceinline__ unsigned int pk2(float lo, float hi) {
    return ((unsigned int)f2bf(hi) << 16) | (unsigned int)f2bf(lo);
}
__device__ __forceinline__ float2 bf2x(unsigned int d) {
    float2 r;
    r.x = __uint_as_float(d << 16);
    r.y = __uint_as_float(d & 0xffff0000u);
    return r;
}
__device__ __forceinline__ float rfl_f(float x) {
    return __uint_as_float(__builtin_amdgcn_readfirstlane(__float_as_uint(x)));
}

#define CC 96
#define SS 16
#define GG 6
#define BN_INV 0.99999500003749969f  // 1/sqrt(1+1e-5)
#define ABLK 512                     // == 2 blocks/CU exactly (VGPR ~172, LDS 79.3KB)
#define TOTW (ABLK * 4)

// gWF image (f32): [0..4799] W2E rows L=0..47 (stride 100, Wp2[c'][2L]),
// [4800..9599] W2O (Wp2[c'][2L+1]), [9600..10199] Wwf rows g (Wpw[ch][g]).
#define GWF_W2O 4800
#define GWF_WW  9600
#define GWF_TOT 10200

// ---------------- kernel 0: prep (weights repack + tiny precompute) ----------------
__global__ __launch_bounds__(256) void prep_kernel(
    const float* __restrict__ Wq, const float* __restrict__ Wk, const float* __restrict__ Wv,
    const float* __restrict__ Wp2, const float* __restrict__ Ww1,
    const float* __restrict__ bp2, const float* __restrict__ bw1,
    u16* __restrict__ WcatT, float* __restrict__ gWF, float* __restrict__ cvec)
{
    int t = blockIdx.x * 256 + threadIdx.x;
    if (t < 13824) {
        // WcatT[c][j] bf16, row-major [288][96]; dword idx = c*48 + j2
        int c = t / 48, j2 = t % 48;
        const float* src = (c < 96) ? Wq : (c < 192) ? Wk : Wv;
        int cc = c % 96;
        float a = src[(2 * j2) * CC + cc];
        float b = src[(2 * j2 + 1) * CC + cc];
        ((unsigned int*)WcatT)[t] = pk2(a, b);
    } else if (t < 13824 + GWF_TOT) {
        int i = t - 13824;
        if (i < GWF_WW) {
            int half = i / GWF_W2O;          // 0 = even channel, 1 = odd
            int r = i % GWF_W2O;
            int L = r / 100, cp = r % 100;
            float v = 0.f;
            if (cp < 96) v = Wp2[cp * CC + 2 * L + half];
            gWF[i] = v;
        } else {
            int r = i - GWF_WW;
            int g = r / 100, ch = r % 100;
            float v = 0.f;
            if (ch < 96) {
                float a = 0.f;
                for (int c = 0; c < CC; ++c)
                    a = fmaf(Wp2[ch * CC + c], Ww1[c * GG + g], a);
                v = a;
            }
            gWF[i] = v;
        }
    } else if (t < 13824 + GWF_TOT + GG) {
        int g = t - (13824 + GWF_TOT);
        float acc = bw1[g];
        for (int c = 0; c < CC; ++c)
            acc = fmaf(bp2[c], Ww1[c * GG + g], acc);
        cvec[g] = acc;
    }
}

// ---------------- kernel 0b: feat -> bf16 ----------------
__global__ __launch_bounds__(256) void fcvt_kernel(
    const float* __restrict__ feat, u16* __restrict__ featB, int total4)
{
    int i = blockIdx.x * 256 + threadIdx.x;
    if (i < total4) {
        float4 v = *(const float4*)(feat + (size_t)i * 4);
        ushort4 o;
        o.x = f2bf(v.x); o.y = f2bf(v.y); o.z = f2bf(v.z); o.w = f2bf(v.w);
        *(ushort4*)(featB + (size_t)i * 4) = o;
    }
}

// ---------------- kernel 1: fused q|k|v MFMA GEMM + epilogue (r6-proven) ----------------
#define SBS 104
__global__ __launch_bounds__(256, 2) void gemm_qkv(
    const u16* __restrict__ featB, const u16* __restrict__ WcatT,
    const float* __restrict__ bq, const float* __restrict__ gq, const float* __restrict__ betaq,
    const float* __restrict__ bk, const float* __restrict__ gk, const float* __restrict__ betak,
    const float* __restrict__ bv, const float* __restrict__ Ww1,
    u16* __restrict__ v_bf, float* __restrict__ KW1, float* __restrict__ qW1, int N)
{
    __shared__ u16 sB[288 * SBS];
    const int t = threadIdx.x;

    for (int i = t; i < 288 * 12; i += 256) {
        int row = i / 12, c8 = i % 12;
        *(float4*)(sB + row * SBS + c8 * 8) = *(const float4*)(WcatT + row * CC + c8 * 8);
    }
    __syncthreads();

    const int wave = t >> 6, lane = t & 63;
    const int m = lane & 15, quad = lane >> 4;
    const int rowbase = blockIdx.x * 64 + wave * 16;

    int arow = rowbase + m;
    if (arow >= N) arow = 0;

    short8 a[3];
    #pragma unroll
    for (int kk = 0; kk < 3; ++kk)
        a[kk] = *(const short8*)(featB + (size_t)arow * CC + kk * 32 + quad * 8);

    f32x4 acc[18];
    #pragma unroll
    for (int nt = 0; nt < 18; ++nt) acc[nt] = (f32x4){0.f, 0.f, 0.f, 0.f};

    #pragma unroll
    for (int kk = 0; kk < 3; ++kk) {
        #pragma unroll
        for (int nt = 0; nt < 18; ++nt) {
            short8 b = *(const short8*)(sB + (nt * 16 + m) * SBS + kk * 32 + quad * 8);
            acc[nt] = __builtin_amdgcn_mfma_f32_16x16x32_bf16(a[kk], b, acc[nt], 0, 0, 0);
        }
    }

    int orow[4];
    #pragma unroll
    for (int i = 0; i < 4; ++i) orow[i] = rowbase + quad * 4 + i;
    const int cloc = m;

    #pragma unroll
    for (int nt6 = 0; nt6 < 6; ++nt6) {
        int c = nt6 * 16 + cloc;
        float bvv = bv[c];
        #pragma unroll
        for (int i = 0; i < 4; ++i)
            if (orow[i] < N)
                v_bf[(size_t)orow[i] * CC + c] = f2bf(acc[12 + nt6][i] + bvv);
    }

    #pragma unroll
    for (int mat = 0; mat < 2; ++mat) {
        const float* bb_ = mat ? bk : bq;
        const float* gg_ = mat ? gk : gq;
        const float* be_ = mat ? betak : betaq;
        float red[4][6];
        #pragma unroll
        for (int i = 0; i < 4; ++i)
            #pragma unroll
            for (int g = 0; g < 6; ++g) red[i][g] = 0.f;

        #pragma unroll
        for (int nt6 = 0; nt6 < 6; ++nt6) {
            int nt = mat * 6 + nt6;
            int c = nt6 * 16 + cloc;
            float bb = bb_[c], sc = gg_[c] * BN_INV, be = be_[c];
            float w1r[6];
            #pragma unroll
            for (int g = 0; g < 6; ++g) w1r[g] = Ww1[c * GG + g];
            #pragma unroll
            for (int i = 0; i < 4; ++i) {
                float act = fmaxf(0.f, fmaf(acc[nt][i] + bb, sc, be));
                #pragma unroll
                for (int g = 0; g < 6; ++g)
                    red[i][g] = fmaf(act, w1r[g], red[i][g]);
            }
        }
        #pragma unroll
        for (int st = 1; st < 16; st <<= 1)
            #pragma unroll
            for (int i = 0; i < 4; ++i)
                #pragma unroll
                for (int g = 0; g < 6; ++g)
                    red[i][g] += __shfl_xor(red[i][g], st);

        float* dst = mat ? KW1 : qW1;
        #pragma unroll
        for (int g = 0; g < 6; ++g)
            if (cloc == g)
                #pragma unroll
                for (int i = 0; i < 4; ++i)
                    if (orow[i] < N)
                        dst[(size_t)orow[i] * 8 + g] = red[i][g];
    }
}

// ---------------- kernel 2: attention v11 — f32 LDS operands (VALU de-bloat) ----------------
// Occupancy is FIXED at 2 waves/SIMD (r0-r6: natural demand 172; caps spill;
// LDS staging wastes the win). v11 attacks the only loaded pipe (VALU 41%):
// ~600 of ~2750 VALU ops/point were bf16 pack/unpack (bf8x/pk2) + select chains
// on LDS-resident data. All LDS operands (Wp2 E/O copies, Wpw, h, softmax wgt)
// now stored as f32 -> those ops vanish; extra LDS bytes ride the DS pipe.
// LDS 79.3KB -> still exactly 2 blocks/CU. ABLK back to 512 (= 2 blocks/CU,
// r6 showed 768 on a 2-block kernel costs ~13us tail).
__global__ __launch_bounds__(256) void attn_kernel(
    const float* __restrict__ coord, const int* __restrict__ ref,
    const float* __restrict__ Wp1, const float* __restrict__ bp1, const float* __restrict__ gp, const float* __restrict__ betap,
    const float* __restrict__ bp2,
    const float* __restrict__ gw, const float* __restrict__ betaw,
    const float* __restrict__ Ww2, const float* __restrict__ bw2,
    const u16* __restrict__ v_bf, const float* __restrict__ KW1, const float* __restrict__ qW1,
    const float* __restrict__ gWF, const float* __restrict__ cvec,
    float* __restrict__ out, int N)
{
    __shared__ __align__(16) float sWF[GWF_TOT];        // 40800 B: W2E | W2O | Wwf
    __shared__ __align__(16) float shh[4][SS * 100];    // 25600 B  h f32 [s*100 + 2L]
    __shared__ __align__(16) float swtf[4][SS * 8];     // 2048 B   softmax wgt f32 [s*8+g]
    __shared__ __align__(16) float sHs[4][600];         // 9600 B   Hsum [g*100 + 2L]
    __shared__ __align__(16) float4 sposx[4][SS];       // 1024 B
    __shared__ int sidxx[4][SS];                        // 256 B
    // total 79328 B -> 2 blocks/CU

    const int t = threadIdx.x;
    for (int i = t; i < GWF_TOT; i += 256) sWF[i] = gWF[i];
    __syncthreads();   // only block barrier

    const int w = t >> 6, lane = t & 63;
    const int wid = blockIdx.x * 4 + w;
    float* shw = shh[w];
    float* swtw = swtf[w];
    float* sHsw = sHs[w];
    float4* sposw = sposx[w];
    int* sidxw = sidxx[w];

    const int  L = (lane < 48) ? lane : 47;
    const bool actv = lane < 48;
    const int  cA = 2 * L;
    const int  gL = L >> 3;
    const int  s16 = lane & 15, qq = lane >> 4;

    // BN folded into Wp1: h = relu(sp*(dot+b1) + bt) = relu(dot' + b1')
    const float spA = gp[cA] * BN_INV, spB = gp[cA + 1] * BN_INV;
    const float w1xA = Wp1[cA] * spA, w1yA = Wp1[CC + cA] * spA, w1zA = Wp1[2 * CC + cA] * spA;
    const float w1xB = Wp1[cA + 1] * spB, w1yB = Wp1[CC + cA + 1] * spB, w1zB = Wp1[2 * CC + cA + 1] * spB;
    const float b1A = fmaf(bp1[cA], spA, betap[cA]);
    const float b1B = fmaf(bp1[cA + 1], spB, betap[cA + 1]);
    const float bpA = bp2[cA], bpB = bp2[cA + 1];

    // prefetched ref indices for the upcoming iteration
    int idxreg = 0;
    if (lane < SS && wid < N) idxreg = ref[wid * SS + s16];

    for (int n = wid; n < N; n += TOTW) {
        // ---- head: indices, pos, k-row gather ----
        if (lane < SS) sidxw[s16] = idxreg;
        float4 kAv = {0,0,0,0}; float2 kBv = {0,0};
        if (lane < SS) {
            int j = idxreg;
            float4 P;
            P.x = coord[j * 3 + 0] - coord[n * 3 + 0];
            P.y = coord[j * 3 + 1] - coord[n * 3 + 1];
            P.z = coord[j * 3 + 2] - coord[n * 3 + 2];
            P.w = 0.f;
            sposw[s16] = P;
            const float* kr = KW1 + (size_t)idxreg * 8;
            kAv = *(const float4*)kr; kBv = *(const float2*)(kr + 4);
        }
        // uniform q-row: fold cvec - q into SGPRs (n is wave-uniform)
        float qc[GG];
        {
            int nu = __builtin_amdgcn_readfirstlane(n);
            const float* qr = qW1 + (size_t)nu * 8;
            #pragma unroll
            for (int g = 0; g < GG; ++g)
                qc[g] = rfl_f(cvec[g] - qr[g]);
        }
        // issue next iteration's ref load now; result consumed next iteration
        {
            int nn = n + TOTW;
            if (lane < SS && nn < N) idxreg = ref[nn * SS + s16];
        }

        // ---- stage 1: h = relu(pos@Wp1' + b1') -> f32 pairs in LDS ----
        if (actv) {
            #pragma unroll
            for (int s = 0; s < SS; ++s) {
                float4 P = sposw[s];                 // broadcast b128
                float hA = fmaxf(0.f, fmaf(P.x, w1xA, fmaf(P.y, w1yA, fmaf(P.z, w1zA, b1A))));
                float hB = fmaxf(0.f, fmaf(P.x, w1xB, fmaf(P.y, w1yB, fmaf(P.z, w1zB, b1B))));
                *(float2*)(shw + s * 100 + cA) = make_float2(hA, hB);
            }
        }

        // ---- stage 2 main: logits, f32 operands, 8-channel chunks ----
        float acc[GG];
        {
            const float* hrow = shw + 100 * s16 + 24 * qq;
            const float* wbase = sWF + GWF_WW + 24 * qq;
            #pragma unroll
            for (int g = 0; g < GG; ++g) acc[g] = 0.f;
            #pragma unroll
            for (int c3 = 0; c3 < 3; ++c3) {
                float4 h0 = *(const float4*)(hrow + 8 * c3);
                float4 h1 = *(const float4*)(hrow + 8 * c3 + 4);
                #pragma unroll
                for (int g = 0; g < GG; ++g) {
                    const float* wr = wbase + g * 100 + 8 * c3;
                    float4 w0 = *(const float4*)(wr);      // broadcast (4 addrs/wave)
                    float4 w1 = *(const float4*)(wr + 4);
                    float a = acc[g];
                    a = fmaf(h0.x, w0.x, a); a = fmaf(h0.y, w0.y, a);
                    a = fmaf(h0.z, w0.z, a); a = fmaf(h0.w, w0.w, a);
                    a = fmaf(h1.x, w1.x, a); a = fmaf(h1.y, w1.y, a);
                    a = fmaf(h1.z, w1.z, a); a = fmaf(h1.w, w1.w, a);
                    acc[g] = a;
                }
            }
            #pragma unroll
            for (int g = 0; g < GG; ++g) {
                acc[g] += __shfl_xor(acc[g], 16);
                acc[g] += __shfl_xor(acc[g], 32);
            }
        }

        // ---- v gather (kept out of the stage-2 register peak) ----
        unsigned int vpre[SS];
        #pragma unroll
        for (int s = 0; s < SS; ++s) {
            int jj = sidxw[s];                       // wave-private, in-order DS
            vpre[s] = *(const unsigned int*)(v_bf + (size_t)jj * CC + cA);
        }

        // ---- stage 2 epilogue: softmax weights (lanes < 16), f32 to LDS ----
        if (lane < SS) {
            float tv[GG];
            tv[0] = acc[0] + kAv.x + qc[0];
            tv[1] = acc[1] + kAv.y + qc[1];
            tv[2] = acc[2] + kAv.z + qc[2];
            tv[3] = acc[3] + kAv.w + qc[3];
            tv[4] = acc[4] + kBv.x + qc[4];
            tv[5] = acc[5] + kBv.y + qc[5];
            float a6[GG];
            #pragma unroll
            for (int g = 0; g < GG; ++g)
                a6[g] = fmaxf(0.f, fmaf(tv[g], gw[g] * BN_INV, betaw[g]));
            float e[GG];
            #pragma unroll
            for (int gg2 = 0; gg2 < GG; ++gg2) {
                float lv = bw2[gg2];
                #pragma unroll
                for (int g2 = 0; g2 < GG; ++g2)
                    lv = fmaf(a6[g2], Ww2[g2 * GG + gg2], lv);
                e[gg2] = __expf(lv);
            }
            float wgt[GG];
            #pragma unroll
            for (int g = 0; g < GG; ++g) {
                float ssum = e[g];
                ssum += __shfl_xor(ssum, 1);
                ssum += __shfl_xor(ssum, 2);
                ssum += __shfl_xor(ssum, 4);
                ssum += __shfl_xor(ssum, 8);
                wgt[g] = e[g] / ssum;
            }
            float4 wt03; wt03.x = wgt[0]; wt03.y = wgt[1]; wt03.z = wgt[2]; wt03.w = wgt[3];
            *(float4*)(swtw + s16 * 8) = wt03;
            *(float2*)(swtw + s16 * 8 + 4) = make_float2(wgt[4], wgt[5]);
        }

        // ---- stage 3+4: Hsum + v-part fused (f32 wgt/h, no unpack/select) ----
        float accA = bpA, accB = bpB;
        {
            float hsA[GG] = {0.f,0.f,0.f,0.f,0.f,0.f};
            float hsB[GG] = {0.f,0.f,0.f,0.f,0.f,0.f};
            #pragma unroll
            for (int s = 0; s < SS; ++s) {
                float4 w03 = *(const float4*)(swtw + s * 8);   // broadcast
                float2 w45 = *(const float2*)(swtw + s * 8 + 4);
                float wsel = swtw[s * 8 + gL];                 // 6 addrs, broadcast groups
                float2 h2 = *(const float2*)(shw + s * 100 + cA);
                hsA[0] = fmaf(w03.x, h2.x, hsA[0]); hsB[0] = fmaf(w03.x, h2.y, hsB[0]);
                hsA[1] = fmaf(w03.y, h2.x, hsA[1]); hsB[1] = fmaf(w03.y, h2.y, hsB[1]);
                hsA[2] = fmaf(w03.z, h2.x, hsA[2]); hsB[2] = fmaf(w03.z, h2.y, hsB[2]);
                hsA[3] = fmaf(w03.w, h2.x, hsA[3]); hsB[3] = fmaf(w03.w, h2.y, hsB[3]);
                hsA[4] = fmaf(w45.x, h2.x, hsA[4]); hsB[4] = fmaf(w45.x, h2.y, hsB[4]);
                hsA[5] = fmaf(w45.y, h2.x, hsA[5]); hsB[5] = fmaf(w45.y, h2.y, hsB[5]);
                float2 v2 = bf2x(vpre[s]);
                accA = fmaf(v2.x, wsel, accA);
                accB = fmaf(v2.y, wsel, accB);
            }
            if (actv) {
                #pragma unroll
                for (int g = 0; g < GG; ++g)
                    *(float2*)(sHsw + g * 100 + cA) = make_float2(hsA[g], hsB[g]);
            }
        }

        // ---- stage 5: out = v-part + Hsum[gL] @ Wp2 cols (f32 E/O copies) ----
        if (actv) {
            const float* hrg = sHsw + gL * 100;
            const float* wE = sWF + L * 100;             // even channel cA
            const float* wO = sWF + GWF_W2O + L * 100;   // odd channel cA+1
            #pragma unroll
            for (int u = 0; u < 12; ++u) {
                float4 hb0 = *(const float4*)(hrg + 8 * u);
                float4 hb1 = *(const float4*)(hrg + 8 * u + 4);
                float4 we0 = *(const float4*)(wE + 8 * u);
                float4 we1 = *(const float4*)(wE + 8 * u + 4);
                float4 wo0 = *(const float4*)(wO + 8 * u);
                float4 wo1 = *(const float4*)(wO + 8 * u + 4);
                accA = fmaf(hb0.x, we0.x, accA); accB = fmaf(hb0.x, wo0.x, accB);
                accA = fmaf(hb0.y, we0.y, accA); accB = fmaf(hb0.y, wo0.y, accB);
                accA = fmaf(hb0.z, we0.z, accA); accB = fmaf(hb0.z, wo0.z, accB);
                accA = fmaf(hb0.w, we0.w, accA); accB = fmaf(hb0.w, wo0.w, accB);
                accA = fmaf(hb1.x, we1.x, accA); accB = fmaf(hb1.x, wo1.x, accB);
                accA = fmaf(hb1.y, we1.y, accA); accB = fmaf(hb1.y, wo1.y, accB);
                accA = fmaf(hb1.z, we1.z, accA); accB = fmaf(hb1.z, wo1.z, accB);
                accA = fmaf(hb1.w, we1.w, accA); accB = fmaf(hb1.w, wo1.w, accB);
            }
            *(float2*)(out + (size_t)n * CC + cA) = make_float2(accA, accB);
        }
    }
}

extern "C" void kernel_launch(void* const* d_in, const int* in_sizes, int n_in,
                              void* d_out, int out_size, void* d_ws, size_t ws_size,
                              hipStream_t stream) {
    const float* feat  = (const float*)d_in[0];
    const float* coord = (const float*)d_in[1];
    const int*   ref   = (const int*)d_in[2];
    const float* Wq = (const float*)d_in[3],  *bq = (const float*)d_in[4],  *gq = (const float*)d_in[5],  *betaq = (const float*)d_in[6];
    const float* Wk = (const float*)d_in[7],  *bk = (const float*)d_in[8],  *gk = (const float*)d_in[9],  *betak = (const float*)d_in[10];
    const float* Wv = (const float*)d_in[11], *bv = (const float*)d_in[12];
    const float* Wp1 = (const float*)d_in[13], *bp1 = (const float*)d_in[14], *gp = (const float*)d_in[15], *betap = (const float*)d_in[16];
    const float* Wp2 = (const float*)d_in[17], *bp2 = (const float*)d_in[18];
    const float* Ww1 = (const float*)d_in[19], *bw1 = (const float*)d_in[20], *gw = (const float*)d_in[21], *betaw = (const float*)d_in[22];
    const float* Ww2 = (const float*)d_in[23], *bw2 = (const float*)d_in[24];

    const int N = in_sizes[0] / CC;   // 50000

    // workspace (~22.5 MB)
    float* wsf = (float*)d_ws;
    float* KW1 = wsf;                                  // N*8 f32
    float* qW1 = KW1 + (size_t)N * 8;                  // N*8 f32
    float* cvec = qW1 + (size_t)N * 8;                 // 6 (pad 32)
    float* gWF = cvec + 32;                            // 10200 (pad 10240)
    u16* WcatT = (u16*)(gWF + 10240);                  // 288*96 bf16
    u16* featB = WcatT + 288 * CC;                     // N*96 bf16
    u16* v_bf = featB + (size_t)N * CC;                // N*96 bf16

    const int prep_total = 13824 + GWF_TOT + GG;
    prep_kernel<<<dim3((prep_total + 255) / 256), dim3(256), 0, stream>>>(
        Wq, Wk, Wv, Wp2, Ww1, bp2, bw1, WcatT, gWF, cvec);

    const int total4 = N * CC / 4;
    fcvt_kernel<<<dim3((total4 + 255) / 256), dim3(256), 0, stream>>>(feat, featB, total4);

    gemm_qkv<<<dim3((N + 63) / 64), dim3(256), 0, stream>>>(
        featB, WcatT, bq, gq, betaq, bk, gk, betak, bv, Ww1,
        v_bf, KW1, qW1, N);

    attn_kernel<<<dim3(ABLK), dim3(256), 0, stream>>>(
        coord, ref, Wp1, bp1, gp, betap, bp2, gw, betaw, Ww2, bw2,
        v_bf, KW1, qW1, gWF, cvec, (float*)d_out, N);
}